// Round 1
// 214.099 us; speedup vs baseline: 1.0254x; 1.0254x over previous
//
#include <hip/hip_runtime.h>
#include <hip/hip_bf16.h>

typedef __hip_bfloat16 bf16;
typedef __attribute__((ext_vector_type(8))) short short8;
typedef __attribute__((ext_vector_type(4))) float floatx4;
typedef __attribute__((ext_vector_type(2))) float floatx2;
typedef unsigned short u16;
typedef unsigned char u8;

#define NNODES 50000
#define NEDGES 800000
#define D_IN  128
#define D_HID 128
#define D_OUT 64
#define NBLK  ((NNODES + 255) / 256)   // 196 scan blocks

__device__ __forceinline__ float bfbits2f(unsigned int u) {
    return __uint_as_float(u << 16);
}
__device__ __forceinline__ float b2f(bf16 v) { return __bfloat162float(v); }
__device__ __forceinline__ unsigned short f2bfbits(float f) {
    bf16 b = __float2bfloat16(f);
    return *(unsigned short*)&b;
}
__device__ __forceinline__ u8 f2fp8(float f) {
    return (u8)(__builtin_amdgcn_cvt_pk_fp8_f32(f, 0.f, 0, false) & 0xFF);
}
__device__ __forceinline__ float ld(const void* p, long long idx, int isf32) {
    if (isf32) return ((const float*)p)[idx];
    return b2f(((const bf16*)p)[idx]);
}
__device__ __forceinline__ short8 a_frag_from(const void* xp, long long elem_off, int isf32) {
    if (!isf32) return *(const short8*)((const bf16*)xp + elem_off);
    const float* f = (const float*)xp + elem_off;
    short8 r;
    #pragma unroll
    for (int j = 0; j < 8; j++) r[j] = (short)f2bfbits(f[j]);
    return r;
}

// ---- setup: zero cnt + detect (blocks 0..127), pack W (128..151),
//      build fp8 x-table (152..) -----------------------------------------
// flags[0] = 1 if edge_index is int64; flags[1] = 1 if float arrays are f32
__global__ void k_setup(int* __restrict__ cnt, int n,
                        const unsigned int* __restrict__ ei_words,
                        const unsigned int* __restrict__ w_words,
                        int* __restrict__ flags,
                        const void* __restrict__ x,
                        const void* __restrict__ W1l, const void* __restrict__ W1r,
                        const void* __restrict__ W2l, const void* __restrict__ W2r,
                        bf16* __restrict__ p1l, bf16* __restrict__ p1r,
                        bf16* __restrict__ p2l, bf16* __restrict__ p2r,
                        unsigned int* __restrict__ x8) {
    int b = blockIdx.x;
    if (b < 128) {
        if (b == 0) {
            __shared__ int cnt_zero, cnt_bf;
            if (threadIdx.x == 0) { cnt_zero = 0; cnt_bf = 0; }
            __syncthreads();
            int t = threadIdx.x;
            unsigned int we = ei_words[2 * t + 1];
            if (we == 0u) atomicAdd(&cnt_zero, 1);
            unsigned int ww = w_words[t];
            unsigned int lowexp = (ww >> 7) & 0xFFu;
            if (lowexp >= 0x60u && lowexp <= 0x7Bu) atomicAdd(&cnt_bf, 1);
            __syncthreads();
            if (threadIdx.x == 0) {
                flags[0] = (cnt_zero >= 240) ? 1 : 0;
                flags[1] = (cnt_bf >= 192) ? 0 : 1;
            }
        }
        int i = b * blockDim.x + threadIdx.x;
        int stride = 128 * blockDim.x;
        for (; i < n; i += stride) cnt[i] = 0;
        return;
    }
    // local dtype detection (flags not yet visible grid-wide)
    __shared__ int cnt_bf2;
    if (threadIdx.x == 0) cnt_bf2 = 0;
    __syncthreads();
    {
        unsigned int ww = w_words[threadIdx.x];
        unsigned int lowexp = (ww >> 7) & 0xFFu;
        if (lowexp >= 0x60u && lowexp <= 0x7Bu) atomicAdd(&cnt_bf2, 1);
    }
    __syncthreads();
    int isf32 = (cnt_bf2 >= 192) ? 0 : 1;
    if (b < 152) {  // ---- weight pack into MFMA B-fragment order
        int t = (b - 128) * 256 + threadIdx.x;
        if (t >= 6144) return;
        const void* Wm; bf16* dst; int NT; int base;
        if (t < 2048)      { Wm = W1l; dst = p1l; NT = 8; base = t; }
        else if (t < 4096) { Wm = W1r; dst = p1r; NT = 8; base = t - 2048; }
        else if (t < 5120) { Wm = W2l; dst = p2l; NT = 4; base = t - 4096; }
        else               { Wm = W2r; dst = p2r; NT = 4; base = t - 5120; }
        int lane = base & 63;
        int kt = (base >> 6) & 3;
        int nt = base >> 8;
        int Nmat = NT * 16;
        int krow = kt * 32 + ((lane >> 4) * 8);
        int col = nt * 16 + (lane & 15);
        #pragma unroll
        for (int j = 0; j < 8; j++) {
            float v = ld(Wm, (long long)(krow + j) * Nmat + col, isf32);
            dst[(((nt * 4 + kt) * 64 + lane) * 8) + j] = __float2bfloat16(v);
        }
        return;
    }
    // ---- fp8 (e4m3) x-table: 4 elems -> 1 u32 per thread, grid-stride
    const long long NU32 = (long long)NNODES * D_IN / 4;  // 1.6M
    long long i = (long long)(b - 152) * 256 + threadIdx.x;
    long long stride = (long long)(gridDim.x - 152) * 256;
    if (isf32) {
        const float4* xf = (const float4*)x;
        for (; i < NU32; i += stride) {
            float4 f = xf[i];
            unsigned int w0 = __builtin_amdgcn_cvt_pk_fp8_f32(f.x, f.y, 0, false);
            w0 = __builtin_amdgcn_cvt_pk_fp8_f32(f.z, f.w, w0, true);
            x8[i] = w0;
        }
    } else {
        const ushort4* xb = (const ushort4*)x;
        for (; i < NU32; i += stride) {
            ushort4 s = xb[i];
            float f0 = bfbits2f(s.x), f1 = bfbits2f(s.y);
            float f2 = bfbits2f(s.z), f3 = bfbits2f(s.w);
            unsigned int w0 = __builtin_amdgcn_cvt_pk_fp8_f32(f0, f1, 0, false);
            w0 = __builtin_amdgcn_cvt_pk_fp8_f32(f2, f3, w0, true);
            x8[i] = w0;
        }
    }
}

// ------- edges: canonicalize + histogram + per-edge rank (packed w/ dst) ----
// drpack[e] = (rank << 16) | dst   (both < 65536)
__global__ void k_edges(const int* __restrict__ ei, const int* __restrict__ flags,
                        u16* __restrict__ src16, unsigned int* __restrict__ drpack,
                        int* __restrict__ cnt) {
    int e = blockIdx.x * blockDim.x + threadIdx.x;
    if (e >= NEDGES) return;
    int s, d;
    if (flags[0]) { s = ei[2 * e]; d = ei[2 * (NEDGES + e)]; }
    else          { s = ei[e];     d = ei[NEDGES + e]; }
    src16[e] = (u16)s;
    int rank = atomicAdd(&cnt[d], 1);
    drpack[e] = ((unsigned int)rank << 16) | (unsigned int)d;
}

// ---------------- 2-phase exclusive scan ----------------
__global__ void k_scan_a(const int* __restrict__ cnt, int* __restrict__ excl,
                         int* __restrict__ bsum) {
    __shared__ int s[256];
    int t = threadIdx.x;
    int i = blockIdx.x * 256 + t;
    int v = (i < NNODES) ? cnt[i] : 0;
    s[t] = v;
    __syncthreads();
    for (int off = 1; off < 256; off <<= 1) {
        int u = (t >= off) ? s[t - off] : 0;
        __syncthreads();
        s[t] += u;
        __syncthreads();
    }
    if (i < NNODES) excl[i] = s[t] - v;
    if (t == 255) bsum[blockIdx.x] = s[255];
}

// every block scans bsum in LDS (redundant but cheap), picks its offset,
// then writes row_start — merges old scan_b+scan_c into one launch
__global__ void k_scan_bc(const int* __restrict__ excl, const int* __restrict__ bsum,
                          int* __restrict__ row_start) {
    __shared__ int s[256];
    __shared__ int bo;
    int t = threadIdx.x;
    int v = (t < NBLK) ? bsum[t] : 0;
    s[t] = v;
    __syncthreads();
    for (int off = 1; off < 256; off <<= 1) {
        int u = (t >= off) ? s[t - off] : 0;
        __syncthreads();
        s[t] += u;
        __syncthreads();
    }
    if (t == 0) bo = s[blockIdx.x] - bsum[blockIdx.x];   // exclusive offset
    __syncthreads();
    int i = blockIdx.x * 256 + t;
    if (i < NNODES) row_start[i] = bo + excl[i];
    if (i == 0) row_start[NNODES] = NEDGES;
}

// ---------------- scatter edges into u16 CSR (no atomics) ----------------
__global__ void k_scatter(const u16* __restrict__ src16,
                          const unsigned int* __restrict__ drpack,
                          const int* __restrict__ row_start,
                          u16* __restrict__ csr16) {
    int e = blockIdx.x * blockDim.x + threadIdx.x;
    if (e >= NEDGES) return;
    unsigned int dp = drpack[e];
    int d = (int)(dp & 0xFFFFu);
    int r = (int)(dp >> 16);
    csr16[row_start[d] + r] = src16[e];
}

// -------- fused: fp8 CSR mean-gather (LDS) + MFMA layer1 + pre-transforms --
// 16 nodes/block, 4 waves. Phase 1: wave w gathers fp8 means of nodes
// w*4..w*4+3 into LDS (bf16). NEW: u32 loads, half-wave per row — lanes
// h=l>>5 split neighbor groups, c=l&31 covers dims 4c..4c+3. 8 loads cover
// 16 neighbors (vs 8 with u16), so an avg-degree-16 node completes in ONE
// unrolled round; per-neighbor shfl+load count halves.
// Phase 2 (MFMA):
//   H  = relu(mean @ W1_l + b1 + x @ W1_r)   [16 x 128] (LDS only; x full-prec)
//   H2 = H @ W2_l                             [16 x 64]  -> h28 (fp8: 1 line/row)
//   HR = H @ W2_r + b2                        [16 x 64]  -> hrf (f32)
__global__ __launch_bounds__(256) void k_l1fused(
        const int* __restrict__ row_start, const u16* __restrict__ csr16,
        const void* __restrict__ x, const unsigned int* __restrict__ x8w,
        const int* __restrict__ flags,
        const bf16* __restrict__ p1l, const bf16* __restrict__ p1r,
        const bf16* __restrict__ p2l, const bf16* __restrict__ p2r,
        const void* __restrict__ b1, const void* __restrict__ b2v,
        u8* __restrict__ h28, float* __restrict__ hrf) {
    __shared__ bf16 ms[16][136];   // +8 pad -> 2-way-free LDS banking
    __shared__ bf16 hs[16][136];
    __shared__ u8 h2s8[16][72];    // 72 = 8*9: rows stay 8B-aligned
    __shared__ float hrs[16][68];
    int t = threadIdx.x;
    int w = t >> 6;
    int l = t & 63;
    int nb = blockIdx.x * 16;
    int isf32 = flags[1];
    int h = l >> 5;    // neighbor-group half (0/1)
    int c = l & 31;    // u32 column -> dims 4c..4c+3

    // hoist the 5 row_start values this wave needs (one coop load + shfl)
    int rsv = row_start[nb + w * 4 + min(l, 4)];

    // ---- phase 1: fp8 gather, 16 neighbors per unrolled round
    for (int i = 0; i < 4; i++) {
        int ln = w * 4 + i;
        int s0 = __shfl(rsv, i), s1 = __shfl(rsv, i + 1);
        float a0 = 0.f, a1 = 0.f, a2 = 0.f, a3 = 0.f;
        for (int base = s0; base < s1; base += 64) {
            int cnt2 = min(64, s1 - base);
            int my = (l < cnt2) ? (int)csr16[base + l] : 0;
            int j = 0;
            for (; j + 15 < cnt2; j += 16) {       // 8 loads -> 16 neighbors
                int jb = j + h * 8;
                int i0 = __shfl(my, jb + 0), i1 = __shfl(my, jb + 1);
                int i2 = __shfl(my, jb + 2), i3 = __shfl(my, jb + 3);
                int i4 = __shfl(my, jb + 4), i5 = __shfl(my, jb + 5);
                int i6 = __shfl(my, jb + 6), i7 = __shfl(my, jb + 7);
                unsigned int u0 = x8w[(size_t)i0 * 32 + c];
                unsigned int u1 = x8w[(size_t)i1 * 32 + c];
                unsigned int u2 = x8w[(size_t)i2 * 32 + c];
                unsigned int u3 = x8w[(size_t)i3 * 32 + c];
                unsigned int u4 = x8w[(size_t)i4 * 32 + c];
                unsigned int u5 = x8w[(size_t)i5 * 32 + c];
                unsigned int u6 = x8w[(size_t)i6 * 32 + c];
                unsigned int u7 = x8w[(size_t)i7 * 32 + c];
                floatx2 l0 = __builtin_amdgcn_cvt_pk_f32_fp8(u0, false);
                floatx2 h0 = __builtin_amdgcn_cvt_pk_f32_fp8(u0, true);
                floatx2 l1 = __builtin_amdgcn_cvt_pk_f32_fp8(u1, false);
                floatx2 h1 = __builtin_amdgcn_cvt_pk_f32_fp8(u1, true);
                floatx2 l2 = __builtin_amdgcn_cvt_pk_f32_fp8(u2, false);
                floatx2 h2 = __builtin_amdgcn_cvt_pk_f32_fp8(u2, true);
                floatx2 l3 = __builtin_amdgcn_cvt_pk_f32_fp8(u3, false);
                floatx2 h3 = __builtin_amdgcn_cvt_pk_f32_fp8(u3, true);
                floatx2 l4 = __builtin_amdgcn_cvt_pk_f32_fp8(u4, false);
                floatx2 h4 = __builtin_amdgcn_cvt_pk_f32_fp8(u4, true);
                floatx2 l5 = __builtin_amdgcn_cvt_pk_f32_fp8(u5, false);
                floatx2 h5 = __builtin_amdgcn_cvt_pk_f32_fp8(u5, true);
                floatx2 l6 = __builtin_amdgcn_cvt_pk_f32_fp8(u6, false);
                floatx2 h6 = __builtin_amdgcn_cvt_pk_f32_fp8(u6, true);
                floatx2 l7 = __builtin_amdgcn_cvt_pk_f32_fp8(u7, false);
                floatx2 h7 = __builtin_amdgcn_cvt_pk_f32_fp8(u7, true);
                a0 += l0.x + l1.x + l2.x + l3.x + l4.x + l5.x + l6.x + l7.x;
                a1 += l0.y + l1.y + l2.y + l3.y + l4.y + l5.y + l6.y + l7.y;
                a2 += h0.x + h1.x + h2.x + h3.x + h4.x + h5.x + h6.x + h7.x;
                a3 += h0.y + h1.y + h2.y + h3.y + h4.y + h5.y + h6.y + h7.y;
            }
            for (; j + 7 < cnt2; j += 8) {         // 4 loads -> 8 neighbors
                int jb = j + h * 4;
                int i0 = __shfl(my, jb + 0), i1 = __shfl(my, jb + 1);
                int i2 = __shfl(my, jb + 2), i3 = __shfl(my, jb + 3);
                unsigned int u0 = x8w[(size_t)i0 * 32 + c];
                unsigned int u1 = x8w[(size_t)i1 * 32 + c];
                unsigned int u2 = x8w[(size_t)i2 * 32 + c];
                unsigned int u3 = x8w[(size_t)i3 * 32 + c];
                floatx2 l0 = __builtin_amdgcn_cvt_pk_f32_fp8(u0, false);
                floatx2 h0 = __builtin_amdgcn_cvt_pk_f32_fp8(u0, true);
                floatx2 l1 = __builtin_amdgcn_cvt_pk_f32_fp8(u1, false);
                floatx2 h1 = __builtin_amdgcn_cvt_pk_f32_fp8(u1, true);
                floatx2 l2 = __builtin_amdgcn_cvt_pk_f32_fp8(u2, false);
                floatx2 h2 = __builtin_amdgcn_cvt_pk_f32_fp8(u2, true);
                floatx2 l3 = __builtin_amdgcn_cvt_pk_f32_fp8(u3, false);
                floatx2 h3 = __builtin_amdgcn_cvt_pk_f32_fp8(u3, true);
                a0 += l0.x + l1.x + l2.x + l3.x;
                a1 += l0.y + l1.y + l2.y + l3.y;
                a2 += h0.x + h1.x + h2.x + h3.x;
                a3 += h0.y + h1.y + h2.y + h3.y;
            }
            for (; j + 1 < cnt2; j += 2) {         // 1 load -> 2 neighbors
                int i0 = __shfl(my, j + h);
                unsigned int u0 = x8w[(size_t)i0 * 32 + c];
                floatx2 l0 = __builtin_amdgcn_cvt_pk_f32_fp8(u0, false);
                floatx2 h0 = __builtin_amdgcn_cvt_pk_f32_fp8(u0, true);
                a0 += l0.x; a1 += l0.y; a2 += h0.x; a3 += h0.y;
            }
            if (j < cnt2) {                        // odd single: half 0 only
                int i0 = __shfl(my, j);
                unsigned int u0 = x8w[(size_t)i0 * 32 + c];
                floatx2 l0 = __builtin_amdgcn_cvt_pk_f32_fp8(u0, false);
                floatx2 h0 = __builtin_amdgcn_cvt_pk_f32_fp8(u0, true);
                if (h == 0) { a0 += l0.x; a1 += l0.y; a2 += h0.x; a3 += h0.y; }
            }
        }
        a0 += __shfl_xor(a0, 32);
        a1 += __shfl_xor(a1, 32);
        a2 += __shfl_xor(a2, 32);
        a3 += __shfl_xor(a3, 32);
        if (l < 32) {
            float inv = 1.0f / fmaxf((float)(s1 - s0), 1.0f);
            uint2 pk;
            pk.x = ((unsigned int)f2bfbits(a1 * inv) << 16) | f2bfbits(a0 * inv);
            pk.y = ((unsigned int)f2bfbits(a3 * inv) << 16) | f2bfbits(a2 * inv);
            *(uint2*)((bf16*)&ms[ln][0] + (c << 2)) = pk;
        }
    }
    __syncthreads();

    // ---- phase 2: MFMA
    int m = l & 15;
    int quad = l >> 4;
    floatx4 acc0 = {0.f, 0.f, 0.f, 0.f};
    floatx4 acc1 = {0.f, 0.f, 0.f, 0.f};
    short8 am[4], ax[4];
    long long rowoff = (long long)(nb + m) * D_IN;
    #pragma unroll
    for (int kt = 0; kt < 4; kt++) {
        am[kt] = *(const short8*)&ms[m][kt * 32 + quad * 8];
        ax[kt] = a_frag_from(x, rowoff + kt * 32 + quad * 8, isf32);
    }
    int nt0 = w * 2, nt1 = w * 2 + 1;
    #pragma unroll
    for (int kt = 0; kt < 4; kt++) {
        short8 bl0 = *(const short8*)(p1l + (((nt0 * 4 + kt) * 64 + l) * 8));
        short8 br0 = *(const short8*)(p1r + (((nt0 * 4 + kt) * 64 + l) * 8));
        acc0 = __builtin_amdgcn_mfma_f32_16x16x32_bf16(am[kt], bl0, acc0, 0, 0, 0);
        acc0 = __builtin_amdgcn_mfma_f32_16x16x32_bf16(ax[kt], br0, acc0, 0, 0, 0);
        short8 bl1 = *(const short8*)(p1l + (((nt1 * 4 + kt) * 64 + l) * 8));
        short8 br1 = *(const short8*)(p1r + (((nt1 * 4 + kt) * 64 + l) * 8));
        acc1 = __builtin_amdgcn_mfma_f32_16x16x32_bf16(am[kt], bl1, acc1, 0, 0, 0);
        acc1 = __builtin_amdgcn_mfma_f32_16x16x32_bf16(ax[kt], br1, acc1, 0, 0, 0);
    }
    int c0 = nt0 * 16 + m;
    int c1 = nt1 * 16 + m;
    float bias0 = ld(b1, c0, isf32);
    float bias1 = ld(b1, c1, isf32);
    #pragma unroll
    for (int r = 0; r < 4; r++) {
        int row = quad * 4 + r;
        hs[row][c0] = __float2bfloat16(fmaxf(acc0[r] + bias0, 0.f));
        hs[row][c1] = __float2bfloat16(fmaxf(acc1[r] + bias1, 0.f));
    }
    __syncthreads();
    floatx4 acc2 = {0.f, 0.f, 0.f, 0.f};
    floatx4 acc3 = {0.f, 0.f, 0.f, 0.f};
    #pragma unroll
    for (int kt = 0; kt < 4; kt++) {
        short8 ah = *(const short8*)&hs[m][kt * 32 + quad * 8];
        short8 bw = *(const short8*)(p2l + (((w * 4 + kt) * 64 + l) * 8));
        short8 bz = *(const short8*)(p2r + (((w * 4 + kt) * 64 + l) * 8));
        acc2 = __builtin_amdgcn_mfma_f32_16x16x32_bf16(ah, bw, acc2, 0, 0, 0);
        acc3 = __builtin_amdgcn_mfma_f32_16x16x32_bf16(ah, bz, acc3, 0, 0, 0);
    }
    int c2 = w * 16 + m;
    float bias2 = ld(b2v, c2, isf32);
    #pragma unroll
    for (int r = 0; r < 4; r++) {
        h2s8[quad * 4 + r][c2] = f2fp8(acc2[r]);      // f32 -> fp8 direct
        hrs[quad * 4 + r][c2] = acc3[r] + bias2;
    }
    __syncthreads();
    if (t < 128) {
        int node = t >> 3, col0 = (t & 7) * 8;
        uint2 v = *(const uint2*)&h2s8[node][col0];
        *(uint2*)(h28 + (long long)(nb + node) * D_OUT + col0) = v;
    }
    {
        int node = t >> 4, col0 = (t & 15) * 4;
        float4 v = *(const float4*)&hrs[node][col0];
        *(float4*)(hrf + (long long)(nb + node) * D_OUT + col0) = v;
    }
}

// ---------------- layer-2 aggregation + add hr ----------------------------
// one wave per node. NEW: u32 loads, quarter-wave per row — 16 lanes cover a
// 64 B fp8 row (dims 4c..4c+3 per lane), groups g=0..3 take 4 neighbors per
// load instruction. A degree-16 node gathers in ONE 4-load round (vs 16
// 1-byte loads before). Two-stage shfl_xor reduce; lanes<16 write float4.
__global__ void k_agg2g(const int* __restrict__ row_start, const u16* __restrict__ csr16,
                        const u8* __restrict__ h28, const float* __restrict__ hrf,
                        const int* __restrict__ flags, void* __restrict__ out) {
    int t = threadIdx.x;
    int lane = t & 63;
    int node = blockIdx.x * 4 + (t >> 6);
    int g = lane >> 4;   // neighbor group 0..3
    int c = lane & 15;   // u32 column -> dims 4c..4c+3
    const unsigned int* h32 = (const unsigned int*)h28;
    int s0 = row_start[node], s1 = row_start[node + 1];
    float a0 = 0.f, a1 = 0.f, a2 = 0.f, a3 = 0.f;
    for (int base = s0; base < s1; base += 64) {
        int cnt2 = min(64, s1 - base);
        int my = (lane < cnt2) ? (int)csr16[base + lane] : 0;
        int j = 0;
        for (; j + 15 < cnt2; j += 16) {          // 4 loads -> 16 neighbors
            int i0 = __shfl(my, j + g);
            int i1 = __shfl(my, j + 4 + g);
            int i2 = __shfl(my, j + 8 + g);
            int i3 = __shfl(my, j + 12 + g);
            unsigned int u0 = h32[(size_t)i0 * 16 + c];
            unsigned int u1 = h32[(size_t)i1 * 16 + c];
            unsigned int u2 = h32[(size_t)i2 * 16 + c];
            unsigned int u3 = h32[(size_t)i3 * 16 + c];
            floatx2 l0 = __builtin_amdgcn_cvt_pk_f32_fp8(u0, false);
            floatx2 h0 = __builtin_amdgcn_cvt_pk_f32_fp8(u0, true);
            floatx2 l1 = __builtin_amdgcn_cvt_pk_f32_fp8(u1, false);
            floatx2 h1 = __builtin_amdgcn_cvt_pk_f32_fp8(u1, true);
            floatx2 l2 = __builtin_amdgcn_cvt_pk_f32_fp8(u2, false);
            floatx2 h2 = __builtin_amdgcn_cvt_pk_f32_fp8(u2, true);
            floatx2 l3 = __builtin_amdgcn_cvt_pk_f32_fp8(u3, false);
            floatx2 h3 = __builtin_amdgcn_cvt_pk_f32_fp8(u3, true);
            a0 += l0.x + l1.x + l2.x + l3.x;
            a1 += l0.y + l1.y + l2.y + l3.y;
            a2 += h0.x + h1.x + h2.x + h3.x;
            a3 += h0.y + h1.y + h2.y + h3.y;
        }
        for (; j + 7 < cnt2; j += 8) {            // 2 loads -> 8 neighbors
            int i0 = __shfl(my, j + g);
            int i1 = __shfl(my, j + 4 + g);
            unsigned int u0 = h32[(size_t)i0 * 16 + c];
            unsigned int u1 = h32[(size_t)i1 * 16 + c];
            floatx2 l0 = __builtin_amdgcn_cvt_pk_f32_fp8(u0, false);
            floatx2 h0 = __builtin_amdgcn_cvt_pk_f32_fp8(u0, true);
            floatx2 l1 = __builtin_amdgcn_cvt_pk_f32_fp8(u1, false);
            floatx2 h1 = __builtin_amdgcn_cvt_pk_f32_fp8(u1, true);
            a0 += l0.x + l1.x; a1 += l0.y + l1.y;
            a2 += h0.x + h1.x; a3 += h0.y + h1.y;
        }
        for (; j < cnt2; j += 4) {                // predicated tail (<=3 iters)
            int jj = j + g;
            float mk = (jj < cnt2) ? 1.0f : 0.0f;
            int i0 = __shfl(my, jj & 63);
            unsigned int u0 = h32[(size_t)i0 * 16 + c];
            floatx2 l0 = __builtin_amdgcn_cvt_pk_f32_fp8(u0, false);
            floatx2 h0 = __builtin_amdgcn_cvt_pk_f32_fp8(u0, true);
            a0 += mk * l0.x; a1 += mk * l0.y;
            a2 += mk * h0.x; a3 += mk * h0.y;
        }
    }
    a0 += __shfl_xor(a0, 32); a0 += __shfl_xor(a0, 16);
    a1 += __shfl_xor(a1, 32); a1 += __shfl_xor(a1, 16);
    a2 += __shfl_xor(a2, 32); a2 += __shfl_xor(a2, 16);
    a3 += __shfl_xor(a3, 32); a3 += __shfl_xor(a3, 16);
    if (lane < 16) {
        float inv = 1.0f / fmaxf((float)(s1 - s0), 1.0f);
        const float4 hr = *(const float4*)&hrf[(size_t)node * D_OUT + (c << 2)];
        float o0 = a0 * inv + hr.x;
        float o1 = a1 * inv + hr.y;
        float o2 = a2 * inv + hr.z;
        float o3 = a3 * inv + hr.w;
        if (flags[1]) {
            float4 v = {o0, o1, o2, o3};
            *(float4*)((float*)out + (size_t)node * D_OUT + (c << 2)) = v;
        } else {
            uint2 v;
            v.x = ((unsigned int)f2bfbits(o1) << 16) | f2bfbits(o0);
            v.y = ((unsigned int)f2bfbits(o3) << 16) | f2bfbits(o2);
            *(uint2*)((bf16*)out + (size_t)node * D_OUT + (c << 2)) = v;
        }
    }
}

extern "C" void kernel_launch(void* const* d_in, const int* in_sizes, int n_in,
                              void* d_out, int out_size, void* d_ws, size_t ws_size,
                              hipStream_t stream) {
    const void* x   = d_in[0];
    const int*  ei  = (const int*)d_in[1];
    const void* W1l = d_in[2];
    const void* b1  = d_in[3];
    const void* W1r = d_in[4];
    const void* W2l = d_in[5];
    const void* b2v = d_in[6];
    const void* W2r = d_in[7];

    const int N = NNODES;
    const int E = NEDGES;

    // ws layout (int units; large arrays 16B-aligned):
    int*          flags     = (int*)d_ws;
    u16*          src16     = (u16*)(flags + 4);            // E u16
    unsigned int* drpack    = (unsigned int*)(src16 + E);   // E u32
    int*          cnt       = (int*)(drpack + E);           // N
    int*          excl      = cnt + N;
    int*          bsum      = excl + N;
    int*          row_start = bsum + 256;                   // N+16
    u16*          csr16     = (u16*)(row_start + (N + 16)); // E u16
    bf16*         p1l       = (bf16*)(csr16 + E);           // 16384 bf16
    bf16*         p1r       = p1l + 16384;
    bf16*         p2l       = p1r + 16384;                  // 8192 bf16
    bf16*         p2r       = p2l + 8192;                   // 8192 bf16
    unsigned int* x8        = (unsigned int*)(p2r + 8192);  // N*128/4 u32
    u8*           h28       = (u8*)(x8 + (size_t)N * D_IN / 4);   // N*64 fp8
    float*        hrf       = (float*)(h28 + (size_t)N * D_OUT);  // N*64 f32

    k_setup<<<152 + 1024, 256, 0, stream>>>(cnt, N, (const unsigned int*)ei,
                                            (const unsigned int*)W1l, flags, x,
                                            W1l, W1r, W2l, W2r,
                                            p1l, p1r, p2l, p2r, x8);
    k_edges<<<(E + 255) / 256, 256, 0, stream>>>(ei, flags, src16, drpack, cnt);
    k_scan_a<<<NBLK, 256, 0, stream>>>(cnt, excl, bsum);
    k_scan_bc<<<NBLK, 256, 0, stream>>>(excl, bsum, row_start);
    k_scatter<<<(E + 255) / 256, 256, 0, stream>>>(src16, drpack, row_start, csr16);
    k_l1fused<<<N / 16, 256, 0, stream>>>(row_start, csr16, x, x8, flags,
                                          p1l, p1r, p2l, p2r, b1, b2v, h28, hrf);
    k_agg2g<<<N / 4, 256, 0, stream>>>(row_start, csr16, h28, hrf, flags, d_out);
}

// Round 2
// 203.711 us; speedup vs baseline: 1.0777x; 1.0510x over previous
//
#include <hip/hip_runtime.h>
#include <hip/hip_bf16.h>

typedef __hip_bfloat16 bf16;
typedef __attribute__((ext_vector_type(8))) short short8;
typedef __attribute__((ext_vector_type(4))) float floatx4;
typedef __attribute__((ext_vector_type(2))) float floatx2;
typedef unsigned short u16;
typedef unsigned char u8;

#define NNODES 50000
#define NEDGES 800000
#define D_IN  128
#define D_HID 128
#define D_OUT 64
#define NBLK  ((NNODES + 255) / 256)   // 196 scan blocks

__device__ __forceinline__ float bfbits2f(unsigned int u) {
    return __uint_as_float(u << 16);
}
__device__ __forceinline__ float b2f(bf16 v) { return __bfloat162float(v); }
__device__ __forceinline__ unsigned short f2bfbits(float f) {
    bf16 b = __float2bfloat16(f);
    return *(unsigned short*)&b;
}
__device__ __forceinline__ u8 f2fp8(float f) {
    return (u8)(__builtin_amdgcn_cvt_pk_fp8_f32(f, 0.f, 0, false) & 0xFF);
}
__device__ __forceinline__ float fp8tof(unsigned int u) {
    floatx2 v = __builtin_amdgcn_cvt_pk_f32_fp8(u, false);
    return v.x;
}
__device__ __forceinline__ float ld(const void* p, long long idx, int isf32) {
    if (isf32) return ((const float*)p)[idx];
    return b2f(((const bf16*)p)[idx]);
}

// ---- setup: zero cnt + detect (blocks 0..127), pack W (128..151),
//      build fp8 x-table (152..) -----------------------------------------
// flags[0] = 1 if edge_index is int64; flags[1] = 1 if float arrays are f32
__global__ void k_setup(int* __restrict__ cnt, int n,
                        const unsigned int* __restrict__ ei_words,
                        const unsigned int* __restrict__ w_words,
                        int* __restrict__ flags,
                        const void* __restrict__ x,
                        const void* __restrict__ W1l, const void* __restrict__ W1r,
                        const void* __restrict__ W2l, const void* __restrict__ W2r,
                        bf16* __restrict__ p1l, bf16* __restrict__ p1r,
                        bf16* __restrict__ p2l, bf16* __restrict__ p2r,
                        unsigned int* __restrict__ x8) {
    int b = blockIdx.x;
    if (b < 128) {
        if (b == 0) {
            __shared__ int cnt_zero, cnt_bf;
            if (threadIdx.x == 0) { cnt_zero = 0; cnt_bf = 0; }
            __syncthreads();
            int t = threadIdx.x;
            unsigned int we = ei_words[2 * t + 1];
            if (we == 0u) atomicAdd(&cnt_zero, 1);
            unsigned int ww = w_words[t];
            unsigned int lowexp = (ww >> 7) & 0xFFu;
            if (lowexp >= 0x60u && lowexp <= 0x7Bu) atomicAdd(&cnt_bf, 1);
            __syncthreads();
            if (threadIdx.x == 0) {
                flags[0] = (cnt_zero >= 240) ? 1 : 0;
                flags[1] = (cnt_bf >= 192) ? 0 : 1;
            }
        }
        int i = b * blockDim.x + threadIdx.x;
        int stride = 128 * blockDim.x;
        for (; i < n; i += stride) cnt[i] = 0;
        return;
    }
    // local dtype detection (flags not yet visible grid-wide)
    __shared__ int cnt_bf2;
    if (threadIdx.x == 0) cnt_bf2 = 0;
    __syncthreads();
    {
        unsigned int ww = w_words[threadIdx.x];
        unsigned int lowexp = (ww >> 7) & 0xFFu;
        if (lowexp >= 0x60u && lowexp <= 0x7Bu) atomicAdd(&cnt_bf2, 1);
    }
    __syncthreads();
    int isf32 = (cnt_bf2 >= 192) ? 0 : 1;
    if (b < 152) {  // ---- weight pack into MFMA B-fragment order
        int t = (b - 128) * 256 + threadIdx.x;
        if (t >= 6144) return;
        const void* Wm; bf16* dst; int NT; int base;
        if (t < 2048)      { Wm = W1l; dst = p1l; NT = 8; base = t; }
        else if (t < 4096) { Wm = W1r; dst = p1r; NT = 8; base = t - 2048; }
        else if (t < 5120) { Wm = W2l; dst = p2l; NT = 4; base = t - 4096; }
        else               { Wm = W2r; dst = p2r; NT = 4; base = t - 5120; }
        int lane = base & 63;
        int kt = (base >> 6) & 3;
        int nt = base >> 8;
        int Nmat = NT * 16;
        int krow = kt * 32 + ((lane >> 4) * 8);
        int col = nt * 16 + (lane & 15);
        #pragma unroll
        for (int j = 0; j < 8; j++) {
            float v = ld(Wm, (long long)(krow + j) * Nmat + col, isf32);
            dst[(((nt * 4 + kt) * 64 + lane) * 8) + j] = __float2bfloat16(v);
        }
        return;
    }
    // ---- fp8 (e4m3) x-table: 4 elems -> 1 u32 per thread, grid-stride
    const long long NU32 = (long long)NNODES * D_IN / 4;  // 1.6M
    long long i = (long long)(b - 152) * 256 + threadIdx.x;
    long long stride = (long long)(gridDim.x - 152) * 256;
    if (isf32) {
        const float4* xf = (const float4*)x;
        for (; i < NU32; i += stride) {
            float4 f = xf[i];
            unsigned int w0 = __builtin_amdgcn_cvt_pk_fp8_f32(f.x, f.y, 0, false);
            w0 = __builtin_amdgcn_cvt_pk_fp8_f32(f.z, f.w, w0, true);
            x8[i] = w0;
        }
    } else {
        const ushort4* xb = (const ushort4*)x;
        for (; i < NU32; i += stride) {
            ushort4 s = xb[i];
            float f0 = bfbits2f(s.x), f1 = bfbits2f(s.y);
            float f2 = bfbits2f(s.z), f3 = bfbits2f(s.w);
            unsigned int w0 = __builtin_amdgcn_cvt_pk_fp8_f32(f0, f1, 0, false);
            w0 = __builtin_amdgcn_cvt_pk_fp8_f32(f2, f3, w0, true);
            x8[i] = w0;
        }
    }
}

// ------- edges: canonicalize + histogram + per-edge rank (packed w/ dst) ----
// drpack[e] = (rank << 16) | dst   (both < 65536)
__global__ void k_edges(const int* __restrict__ ei, const int* __restrict__ flags,
                        u16* __restrict__ src16, unsigned int* __restrict__ drpack,
                        int* __restrict__ cnt) {
    int e = blockIdx.x * blockDim.x + threadIdx.x;
    if (e >= NEDGES) return;
    int s, d;
    if (flags[0]) { s = ei[2 * e]; d = ei[2 * (NEDGES + e)]; }
    else          { s = ei[e];     d = ei[NEDGES + e]; }
    src16[e] = (u16)s;
    int rank = atomicAdd(&cnt[d], 1);
    drpack[e] = ((unsigned int)rank << 16) | (unsigned int)d;
}

// ---------------- 2-phase exclusive scan ----------------
__global__ void k_scan_a(const int* __restrict__ cnt, int* __restrict__ excl,
                         int* __restrict__ bsum) {
    __shared__ int s[256];
    int t = threadIdx.x;
    int i = blockIdx.x * 256 + t;
    int v = (i < NNODES) ? cnt[i] : 0;
    s[t] = v;
    __syncthreads();
    for (int off = 1; off < 256; off <<= 1) {
        int u = (t >= off) ? s[t - off] : 0;
        __syncthreads();
        s[t] += u;
        __syncthreads();
    }
    if (i < NNODES) excl[i] = s[t] - v;
    if (t == 255) bsum[blockIdx.x] = s[255];
}

// every block scans bsum in LDS (redundant but cheap), picks its offset,
// then writes row_start — merges old scan_b+scan_c into one launch
__global__ void k_scan_bc(const int* __restrict__ excl, const int* __restrict__ bsum,
                          int* __restrict__ row_start) {
    __shared__ int s[256];
    __shared__ int bo;
    int t = threadIdx.x;
    int v = (t < NBLK) ? bsum[t] : 0;
    s[t] = v;
    __syncthreads();
    for (int off = 1; off < 256; off <<= 1) {
        int u = (t >= off) ? s[t - off] : 0;
        __syncthreads();
        s[t] += u;
        __syncthreads();
    }
    if (t == 0) bo = s[blockIdx.x] - bsum[blockIdx.x];   // exclusive offset
    __syncthreads();
    int i = blockIdx.x * 256 + t;
    if (i < NNODES) row_start[i] = bo + excl[i];
    if (i == 0) row_start[NNODES] = NEDGES;
}

// ---------------- scatter edges into u16 CSR (no atomics) ----------------
__global__ void k_scatter(const u16* __restrict__ src16,
                          const unsigned int* __restrict__ drpack,
                          const int* __restrict__ row_start,
                          u16* __restrict__ csr16) {
    int e = blockIdx.x * blockDim.x + threadIdx.x;
    if (e >= NEDGES) return;
    unsigned int dp = drpack[e];
    int d = (int)(dp & 0xFFFFu);
    int r = (int)(dp >> 16);
    csr16[row_start[d] + r] = src16[e];
}

// gather <=64 neighbors whose indices are already in 'my' (lane j holds idx j)
// lane l accumulates dims 2l, 2l+1 (one u16 = 2 fp8 per row per lane).
__device__ __forceinline__ void gather64(const u16* __restrict__ x8u, int my,
                                         int cnt2, int l, float& a0, float& a1) {
    int j = 0;
    for (; j + 7 < cnt2; j += 8) {
        int i0 = __shfl(my, j + 0), i1 = __shfl(my, j + 1);
        int i2 = __shfl(my, j + 2), i3 = __shfl(my, j + 3);
        int i4 = __shfl(my, j + 4), i5 = __shfl(my, j + 5);
        int i6 = __shfl(my, j + 6), i7 = __shfl(my, j + 7);
        unsigned int u0 = x8u[((unsigned)i0 << 6) + l];
        unsigned int u1 = x8u[((unsigned)i1 << 6) + l];
        unsigned int u2 = x8u[((unsigned)i2 << 6) + l];
        unsigned int u3 = x8u[((unsigned)i3 << 6) + l];
        unsigned int u4 = x8u[((unsigned)i4 << 6) + l];
        unsigned int u5 = x8u[((unsigned)i5 << 6) + l];
        unsigned int u6 = x8u[((unsigned)i6 << 6) + l];
        unsigned int u7 = x8u[((unsigned)i7 << 6) + l];
        floatx2 v0 = __builtin_amdgcn_cvt_pk_f32_fp8(u0, false);
        floatx2 v1 = __builtin_amdgcn_cvt_pk_f32_fp8(u1, false);
        floatx2 v2 = __builtin_amdgcn_cvt_pk_f32_fp8(u2, false);
        floatx2 v3 = __builtin_amdgcn_cvt_pk_f32_fp8(u3, false);
        floatx2 v4 = __builtin_amdgcn_cvt_pk_f32_fp8(u4, false);
        floatx2 v5 = __builtin_amdgcn_cvt_pk_f32_fp8(u5, false);
        floatx2 v6 = __builtin_amdgcn_cvt_pk_f32_fp8(u6, false);
        floatx2 v7 = __builtin_amdgcn_cvt_pk_f32_fp8(u7, false);
        a0 += v0.x + v1.x + v2.x + v3.x + v4.x + v5.x + v6.x + v7.x;
        a1 += v0.y + v1.y + v2.y + v3.y + v4.y + v5.y + v6.y + v7.y;
    }
    for (; j < cnt2; j++) {
        int si = __shfl(my, j);
        unsigned int u = x8u[((unsigned)si << 6) + l];
        floatx2 v = __builtin_amdgcn_cvt_pk_f32_fp8(u, false);
        a0 += v.x; a1 += v.y;
    }
}

// -------- fused: fp8 CSR mean-gather (LDS) + MFMA layer1 + pre-transforms --
// 16 nodes/block, 8 waves (512 thr): wave w gathers nodes w*2, w*2+1 —
// only 2 serial node chains per wave (was 4), with both nodes' index
// vectors prefetched up front (one latency instead of per-node).
// x rows are staged once into LDS (xs) as bf16, killing the 8x-duplicated
// 32 scalar global loads/lane in phase 2.
// Phase 2 (MFMA):
//   H  = relu(mean @ W1_l + b1 + x @ W1_r)   [16 x 128] — wave w owns col-tile w
//   H2 = H @ W2_l                             [16 x 64]  -> h28 (fp8, waves 0-3)
//   HR = H @ W2_r + b2                        [16 x 64]  -> hrf (f32, waves 0-3)
__global__ __launch_bounds__(512) void k_l1fused(
        const int* __restrict__ row_start, const u16* __restrict__ csr16,
        const void* __restrict__ x, const u16* __restrict__ x8u,
        const int* __restrict__ flags,
        const bf16* __restrict__ p1l, const bf16* __restrict__ p1r,
        const bf16* __restrict__ p2l, const bf16* __restrict__ p2r,
        const void* __restrict__ b1, const void* __restrict__ b2v,
        u8* __restrict__ h28, float* __restrict__ hrf) {
    __shared__ bf16 ms[16][136];   // +8 pad -> 2-way-free LDS banking
    __shared__ bf16 xs[16][136];   // staged x rows (bf16)
    __shared__ bf16 hs[16][136];
    __shared__ u8 h2s8[16][72];    // 72 = 8*9: rows stay 8B-aligned
    __shared__ float hrs[16][68];
    int t = threadIdx.x;
    int w = t >> 6;    // 0..7
    int l = t & 63;
    int nb = blockIdx.x * 16;
    int isf32 = flags[1];
    int r0 = w * 2, r1 = r0 + 1;

    // 3 row_start values per wave, one coop load + shfl
    int rsv = row_start[nb + r0 + min(l, 2)];
    int s0 = __shfl(rsv, 0), s1 = __shfl(rsv, 1), s2 = __shfl(rsv, 2);

    // prefetch both nodes' first index chunks (pays idx latency once)
    int ca = min(64, s1 - s0);
    int cb = min(64, s2 - s1);
    int mya = (l < ca) ? (int)csr16[s0 + l] : 0;
    int myb = (l < cb) ? (int)csr16[s1 + l] : 0;

    // stage this wave's two x rows into LDS as bf16 (dims 2l, 2l+1)
    {
        long long ro0 = (long long)(nb + r0) * D_IN + 2 * l;
        long long ro1 = (long long)(nb + r1) * D_IN + 2 * l;
        unsigned int px0, px1;
        if (isf32) {
            float2 v0 = *(const float2*)((const float*)x + ro0);
            float2 v1 = *(const float2*)((const float*)x + ro1);
            px0 = ((unsigned int)f2bfbits(v0.y) << 16) | f2bfbits(v0.x);
            px1 = ((unsigned int)f2bfbits(v1.y) << 16) | f2bfbits(v1.x);
        } else {
            px0 = *(const unsigned int*)((const bf16*)x + ro0);
            px1 = *(const unsigned int*)((const bf16*)x + ro1);
        }
        *(unsigned int*)((bf16*)&xs[r0][0] + 2 * l) = px0;
        *(unsigned int*)((bf16*)&xs[r1][0] + 2 * l) = px1;
    }

    // ---- phase 1: fp8 gather, 2 serial node chains
    float aa0 = 0.f, aa1 = 0.f;
    float bb0 = 0.f, bb1 = 0.f;
    gather64(x8u, mya, ca, l, aa0, aa1);
    gather64(x8u, myb, cb, l, bb0, bb1);
    for (int base = s0 + 64; base < s1; base += 64) {   // rare deg>64 tail
        int cnt2 = min(64, s1 - base);
        int my = (l < cnt2) ? (int)csr16[base + l] : 0;
        gather64(x8u, my, cnt2, l, aa0, aa1);
    }
    for (int base = s1 + 64; base < s2; base += 64) {
        int cnt2 = min(64, s2 - base);
        int my = (l < cnt2) ? (int)csr16[base + l] : 0;
        gather64(x8u, my, cnt2, l, bb0, bb1);
    }
    {
        float inv = 1.0f / fmaxf((float)(s1 - s0), 1.0f);
        unsigned int pk = ((unsigned int)f2bfbits(aa1 * inv) << 16) | f2bfbits(aa0 * inv);
        *(unsigned int*)((bf16*)&ms[r0][0] + 2 * l) = pk;
    }
    {
        float inv = 1.0f / fmaxf((float)(s2 - s1), 1.0f);
        unsigned int pk = ((unsigned int)f2bfbits(bb1 * inv) << 16) | f2bfbits(bb0 * inv);
        *(unsigned int*)((bf16*)&ms[r1][0] + 2 * l) = pk;
    }
    __syncthreads();

    // ---- phase 2: MFMA — wave w owns layer-1 column tile nt = w
    int m = l & 15;
    int quad = l >> 4;
    floatx4 acc0 = {0.f, 0.f, 0.f, 0.f};
    #pragma unroll
    for (int kt = 0; kt < 4; kt++) {
        short8 amv = *(const short8*)&ms[m][kt * 32 + quad * 8];
        short8 axv = *(const short8*)&xs[m][kt * 32 + quad * 8];
        short8 bl0 = *(const short8*)(p1l + (((w * 4 + kt) * 64 + l) * 8));
        short8 br0 = *(const short8*)(p1r + (((w * 4 + kt) * 64 + l) * 8));
        acc0 = __builtin_amdgcn_mfma_f32_16x16x32_bf16(amv, bl0, acc0, 0, 0, 0);
        acc0 = __builtin_amdgcn_mfma_f32_16x16x32_bf16(axv, br0, acc0, 0, 0, 0);
    }
    int c0 = w * 16 + m;
    float bias0 = ld(b1, c0, isf32);
    #pragma unroll
    for (int r = 0; r < 4; r++) {
        hs[quad * 4 + r][c0] = __float2bfloat16(fmaxf(acc0[r] + bias0, 0.f));
    }
    __syncthreads();
    if (w < 4) {       // layer 2: 4 waves cover the 64 output cols
        floatx4 acc2 = {0.f, 0.f, 0.f, 0.f};
        floatx4 acc3 = {0.f, 0.f, 0.f, 0.f};
        #pragma unroll
        for (int kt = 0; kt < 4; kt++) {
            short8 ah = *(const short8*)&hs[m][kt * 32 + quad * 8];
            short8 bw = *(const short8*)(p2l + (((w * 4 + kt) * 64 + l) * 8));
            short8 bz = *(const short8*)(p2r + (((w * 4 + kt) * 64 + l) * 8));
            acc2 = __builtin_amdgcn_mfma_f32_16x16x32_bf16(ah, bw, acc2, 0, 0, 0);
            acc3 = __builtin_amdgcn_mfma_f32_16x16x32_bf16(ah, bz, acc3, 0, 0, 0);
        }
        int c2 = w * 16 + m;
        float bias2 = ld(b2v, c2, isf32);
        #pragma unroll
        for (int r = 0; r < 4; r++) {
            h2s8[quad * 4 + r][c2] = f2fp8(acc2[r]);      // f32 -> fp8 direct
            hrs[quad * 4 + r][c2] = acc3[r] + bias2;
        }
    }
    __syncthreads();
    if (t < 128) {
        int node = t >> 3, col0 = (t & 7) * 8;
        uint2 v = *(const uint2*)&h2s8[node][col0];
        *(uint2*)(h28 + (long long)(nb + node) * D_OUT + col0) = v;
    }
    if (t < 256) {
        int node = t >> 4, col0 = (t & 15) * 4;
        float4 v = *(const float4*)&hrs[node][col0];
        *(float4*)(hrf + (long long)(nb + node) * D_OUT + col0) = v;
    }
}

// ---------------- layer-2 aggregation + add hr ----------------------------
// one wave per node. u32 loads, quarter-wave per row — 16 lanes cover a
// 64 B fp8 row (dims 4c..4c+3 per lane), groups g=0..3 take 4 neighbors per
// load instruction. Two-stage shfl_xor reduce; lanes<16 write float4.
__global__ void k_agg2g(const int* __restrict__ row_start, const u16* __restrict__ csr16,
                        const u8* __restrict__ h28, const float* __restrict__ hrf,
                        const int* __restrict__ flags, void* __restrict__ out) {
    int t = threadIdx.x;
    int lane = t & 63;
    int node = blockIdx.x * 4 + (t >> 6);
    int g = lane >> 4;   // neighbor group 0..3
    int c = lane & 15;   // u32 column -> dims 4c..4c+3
    const unsigned int* h32 = (const unsigned int*)h28;
    int s0 = row_start[node], s1 = row_start[node + 1];
    float a0 = 0.f, a1 = 0.f, a2 = 0.f, a3 = 0.f;
    for (int base = s0; base < s1; base += 64) {
        int cnt2 = min(64, s1 - base);
        int my = (lane < cnt2) ? (int)csr16[base + lane] : 0;
        int j = 0;
        for (; j + 15 < cnt2; j += 16) {          // 4 loads -> 16 neighbors
            int i0 = __shfl(my, j + g);
            int i1 = __shfl(my, j + 4 + g);
            int i2 = __shfl(my, j + 8 + g);
            int i3 = __shfl(my, j + 12 + g);
            unsigned int u0 = h32[(size_t)i0 * 16 + c];
            unsigned int u1 = h32[(size_t)i1 * 16 + c];
            unsigned int u2 = h32[(size_t)i2 * 16 + c];
            unsigned int u3 = h32[(size_t)i3 * 16 + c];
            floatx2 l0 = __builtin_amdgcn_cvt_pk_f32_fp8(u0, false);
            floatx2 h0 = __builtin_amdgcn_cvt_pk_f32_fp8(u0, true);
            floatx2 l1 = __builtin_amdgcn_cvt_pk_f32_fp8(u1, false);
            floatx2 h1 = __builtin_amdgcn_cvt_pk_f32_fp8(u1, true);
            floatx2 l2 = __builtin_amdgcn_cvt_pk_f32_fp8(u2, false);
            floatx2 h2 = __builtin_amdgcn_cvt_pk_f32_fp8(u2, true);
            floatx2 l3 = __builtin_amdgcn_cvt_pk_f32_fp8(u3, false);
            floatx2 h3 = __builtin_amdgcn_cvt_pk_f32_fp8(u3, true);
            a0 += l0.x + l1.x + l2.x + l3.x;
            a1 += l0.y + l1.y + l2.y + l3.y;
            a2 += h0.x + h1.x + h2.x + h3.x;
            a3 += h0.y + h1.y + h2.y + h3.y;
        }
        for (; j + 7 < cnt2; j += 8) {            // 2 loads -> 8 neighbors
            int i0 = __shfl(my, j + g);
            int i1 = __shfl(my, j + 4 + g);
            unsigned int u0 = h32[(size_t)i0 * 16 + c];
            unsigned int u1 = h32[(size_t)i1 * 16 + c];
            floatx2 l0 = __builtin_amdgcn_cvt_pk_f32_fp8(u0, false);
            floatx2 h0 = __builtin_amdgcn_cvt_pk_f32_fp8(u0, true);
            floatx2 l1 = __builtin_amdgcn_cvt_pk_f32_fp8(u1, false);
            floatx2 h1 = __builtin_amdgcn_cvt_pk_f32_fp8(u1, true);
            a0 += l0.x + l1.x; a1 += l0.y + l1.y;
            a2 += h0.x + h1.x; a3 += h0.y + h1.y;
        }
        for (; j < cnt2; j += 4) {                // predicated tail (<=3 iters)
            int jj = j + g;
            float mk = (jj < cnt2) ? 1.0f : 0.0f;
            int i0 = __shfl(my, jj & 63);
            unsigned int u0 = h32[(size_t)i0 * 16 + c];
            floatx2 l0 = __builtin_amdgcn_cvt_pk_f32_fp8(u0, false);
            floatx2 h0 = __builtin_amdgcn_cvt_pk_f32_fp8(u0, true);
            a0 += mk * l0.x; a1 += mk * l0.y;
            a2 += mk * h0.x; a3 += mk * h0.y;
        }
    }
    a0 += __shfl_xor(a0, 32); a0 += __shfl_xor(a0, 16);
    a1 += __shfl_xor(a1, 32); a1 += __shfl_xor(a1, 16);
    a2 += __shfl_xor(a2, 32); a2 += __shfl_xor(a2, 16);
    a3 += __shfl_xor(a3, 32); a3 += __shfl_xor(a3, 16);
    if (lane < 16) {
        float inv = 1.0f / fmaxf((float)(s1 - s0), 1.0f);
        const float4 hr = *(const float4*)&hrf[(size_t)node * D_OUT + (c << 2)];
        float o0 = a0 * inv + hr.x;
        float o1 = a1 * inv + hr.y;
        float o2 = a2 * inv + hr.z;
        float o3 = a3 * inv + hr.w;
        if (flags[1]) {
            float4 v = {o0, o1, o2, o3};
            *(float4*)((float*)out + (size_t)node * D_OUT + (c << 2)) = v;
        } else {
            uint2 v;
            v.x = ((unsigned int)f2bfbits(o1) << 16) | f2bfbits(o0);
            v.y = ((unsigned int)f2bfbits(o3) << 16) | f2bfbits(o2);
            *(uint2*)((bf16*)out + (size_t)node * D_OUT + (c << 2)) = v;
        }
    }
}

extern "C" void kernel_launch(void* const* d_in, const int* in_sizes, int n_in,
                              void* d_out, int out_size, void* d_ws, size_t ws_size,
                              hipStream_t stream) {
    const void* x   = d_in[0];
    const int*  ei  = (const int*)d_in[1];
    const void* W1l = d_in[2];
    const void* b1  = d_in[3];
    const void* W1r = d_in[4];
    const void* W2l = d_in[5];
    const void* b2v = d_in[6];
    const void* W2r = d_in[7];

    const int N = NNODES;
    const int E = NEDGES;

    // ws layout (int units; large arrays 16B-aligned):
    int*          flags     = (int*)d_ws;
    u16*          src16     = (u16*)(flags + 4);            // E u16
    unsigned int* drpack    = (unsigned int*)(src16 + E);   // E u32
    int*          cnt       = (int*)(drpack + E);           // N
    int*          excl      = cnt + N;
    int*          bsum      = excl + N;
    int*          row_start = bsum + 256;                   // N+16
    u16*          csr16     = (u16*)(row_start + (N + 16)); // E u16
    bf16*         p1l       = (bf16*)(csr16 + E);           // 16384 bf16
    bf16*         p1r       = p1l + 16384;
    bf16*         p2l       = p1r + 16384;                  // 8192 bf16
    bf16*         p2r       = p2l + 8192;                   // 8192 bf16
    unsigned int* x8        = (unsigned int*)(p2r + 8192);  // N*128/4 u32
    u8*           h28       = (u8*)(x8 + (size_t)N * D_IN / 4);   // N*64 fp8
    float*        hrf       = (float*)(h28 + (size_t)N * D_OUT);  // N*64 f32

    k_setup<<<152 + 1024, 256, 0, stream>>>(cnt, N, (const unsigned int*)ei,
                                            (const unsigned int*)W1l, flags, x,
                                            W1l, W1r, W2l, W2r,
                                            p1l, p1r, p2l, p2r, x8);
    k_edges<<<(E + 255) / 256, 256, 0, stream>>>(ei, flags, src16, drpack, cnt);
    k_scan_a<<<NBLK, 256, 0, stream>>>(cnt, excl, bsum);
    k_scan_bc<<<NBLK, 256, 0, stream>>>(excl, bsum, row_start);
    k_scatter<<<(E + 255) / 256, 256, 0, stream>>>(src16, drpack, row_start, csr16);
    k_l1fused<<<N / 16, 512, 0, stream>>>(row_start, csr16, x, (const u16*)x8, flags,
                                          p1l, p1r, p2l, p2r, b1, b2v, h28, hrf);
    k_agg2g<<<N / 4, 256, 0, stream>>>(row_start, csr16, h28, hrf, flags, d_out);
}

// Round 3
// 200.824 us; speedup vs baseline: 1.0932x; 1.0144x over previous
//
#include <hip/hip_runtime.h>
#include <hip/hip_bf16.h>

typedef __hip_bfloat16 bf16;
typedef __attribute__((ext_vector_type(8))) short short8;
typedef __attribute__((ext_vector_type(4))) float floatx4;
typedef __attribute__((ext_vector_type(2))) float floatx2;
typedef unsigned short u16;
typedef unsigned char u8;

#define NNODES 50000
#define NEDGES 800000
#define D_IN  128
#define D_HID 128
#define D_OUT 64
#define NBLK  ((NNODES + 255) / 256)   // 196 scan blocks

__device__ __forceinline__ float bfbits2f(unsigned int u) {
    return __uint_as_float(u << 16);
}
__device__ __forceinline__ float b2f(bf16 v) { return __bfloat162float(v); }
__device__ __forceinline__ unsigned short f2bfbits(float f) {
    bf16 b = __float2bfloat16(f);
    return *(unsigned short*)&b;
}
__device__ __forceinline__ u8 f2fp8(float f) {
    return (u8)(__builtin_amdgcn_cvt_pk_fp8_f32(f, 0.f, 0, false) & 0xFF);
}
__device__ __forceinline__ float ld(const void* p, long long idx, int isf32) {
    if (isf32) return ((const float*)p)[idx];
    return b2f(((const bf16*)p)[idx]);
}

// ---- setup: zero cnt + detect (blocks 0..127), pack W (128..151),
//      build fp8 x-table (152..) -----------------------------------------
// flags[0] = 1 if edge_index is int64; flags[1] = 1 if float arrays are f32
__global__ void k_setup(int* __restrict__ cnt, int n,
                        const unsigned int* __restrict__ ei_words,
                        const unsigned int* __restrict__ w_words,
                        int* __restrict__ flags,
                        const void* __restrict__ x,
                        const void* __restrict__ W1l, const void* __restrict__ W1r,
                        const void* __restrict__ W2l, const void* __restrict__ W2r,
                        bf16* __restrict__ p1l, bf16* __restrict__ p1r,
                        bf16* __restrict__ p2l, bf16* __restrict__ p2r,
                        unsigned int* __restrict__ x8) {
    int b = blockIdx.x;
    if (b < 128) {
        if (b == 0) {
            __shared__ int cnt_zero, cnt_bf;
            if (threadIdx.x == 0) { cnt_zero = 0; cnt_bf = 0; }
            __syncthreads();
            int t = threadIdx.x;
            unsigned int we = ei_words[2 * t + 1];
            if (we == 0u) atomicAdd(&cnt_zero, 1);
            unsigned int ww = w_words[t];
            unsigned int lowexp = (ww >> 7) & 0xFFu;
            if (lowexp >= 0x60u && lowexp <= 0x7Bu) atomicAdd(&cnt_bf, 1);
            __syncthreads();
            if (threadIdx.x == 0) {
                flags[0] = (cnt_zero >= 240) ? 1 : 0;
                flags[1] = (cnt_bf >= 192) ? 0 : 1;
            }
        }
        int i = b * blockDim.x + threadIdx.x;
        int stride = 128 * blockDim.x;
        for (; i < n; i += stride) cnt[i] = 0;
        return;
    }
    // local dtype detection (flags not yet visible grid-wide)
    __shared__ int cnt_bf2;
    if (threadIdx.x == 0) cnt_bf2 = 0;
    __syncthreads();
    {
        unsigned int ww = w_words[threadIdx.x];
        unsigned int lowexp = (ww >> 7) & 0xFFu;
        if (lowexp >= 0x60u && lowexp <= 0x7Bu) atomicAdd(&cnt_bf2, 1);
    }
    __syncthreads();
    int isf32 = (cnt_bf2 >= 192) ? 0 : 1;
    if (b < 152) {  // ---- weight pack into MFMA B-fragment order
        int t = (b - 128) * 256 + threadIdx.x;
        if (t >= 6144) return;
        const void* Wm; bf16* dst; int NT; int base;
        if (t < 2048)      { Wm = W1l; dst = p1l; NT = 8; base = t; }
        else if (t < 4096) { Wm = W1r; dst = p1r; NT = 8; base = t - 2048; }
        else if (t < 5120) { Wm = W2l; dst = p2l; NT = 4; base = t - 4096; }
        else               { Wm = W2r; dst = p2r; NT = 4; base = t - 5120; }
        int lane = base & 63;
        int kt = (base >> 6) & 3;
        int nt = base >> 8;
        int Nmat = NT * 16;
        int krow = kt * 32 + ((lane >> 4) * 8);
        int col = nt * 16 + (lane & 15);
        #pragma unroll
        for (int j = 0; j < 8; j++) {
            float v = ld(Wm, (long long)(krow + j) * Nmat + col, isf32);
            dst[(((nt * 4 + kt) * 64 + lane) * 8) + j] = __float2bfloat16(v);
        }
        return;
    }
    // ---- fp8 (e4m3) x-table: 4 elems -> 1 u32 per thread, grid-stride
    const long long NU32 = (long long)NNODES * D_IN / 4;  // 1.6M
    long long i = (long long)(b - 152) * 256 + threadIdx.x;
    long long stride = (long long)(gridDim.x - 152) * 256;
    if (isf32) {
        const float4* xf = (const float4*)x;
        for (; i < NU32; i += stride) {
            float4 f = xf[i];
            unsigned int w0 = __builtin_amdgcn_cvt_pk_fp8_f32(f.x, f.y, 0, false);
            w0 = __builtin_amdgcn_cvt_pk_fp8_f32(f.z, f.w, w0, true);
            x8[i] = w0;
        }
    } else {
        const ushort4* xb = (const ushort4*)x;
        for (; i < NU32; i += stride) {
            ushort4 s = xb[i];
            float f0 = bfbits2f(s.x), f1 = bfbits2f(s.y);
            float f2 = bfbits2f(s.z), f3 = bfbits2f(s.w);
            unsigned int w0 = __builtin_amdgcn_cvt_pk_fp8_f32(f0, f1, 0, false);
            w0 = __builtin_amdgcn_cvt_pk_fp8_f32(f2, f3, w0, true);
            x8[i] = w0;
        }
    }
}

// ------- edges: canonicalize + histogram + per-edge rank (packed w/ dst) ----
// drpack[e] = (rank << 16) | dst   (both < 65536)
__global__ void k_edges(const int* __restrict__ ei, const int* __restrict__ flags,
                        u16* __restrict__ src16, unsigned int* __restrict__ drpack,
                        int* __restrict__ cnt) {
    int e = blockIdx.x * blockDim.x + threadIdx.x;
    if (e >= NEDGES) return;
    int s, d;
    if (flags[0]) { s = ei[2 * e]; d = ei[2 * (NEDGES + e)]; }
    else          { s = ei[e];     d = ei[NEDGES + e]; }
    src16[e] = (u16)s;
    int rank = atomicAdd(&cnt[d], 1);
    drpack[e] = ((unsigned int)rank << 16) | (unsigned int)d;
}

// ---------------- 2-phase exclusive scan ----------------
__global__ void k_scan_a(const int* __restrict__ cnt, int* __restrict__ excl,
                         int* __restrict__ bsum) {
    __shared__ int s[256];
    int t = threadIdx.x;
    int i = blockIdx.x * 256 + t;
    int v = (i < NNODES) ? cnt[i] : 0;
    s[t] = v;
    __syncthreads();
    for (int off = 1; off < 256; off <<= 1) {
        int u = (t >= off) ? s[t - off] : 0;
        __syncthreads();
        s[t] += u;
        __syncthreads();
    }
    if (i < NNODES) excl[i] = s[t] - v;
    if (t == 255) bsum[blockIdx.x] = s[255];
}

// every block scans bsum in LDS (redundant but cheap), picks its offset,
// then writes row_start — merges old scan_b+scan_c into one launch
__global__ void k_scan_bc(const int* __restrict__ excl, const int* __restrict__ bsum,
                          int* __restrict__ row_start) {
    __shared__ int s[256];
    __shared__ int bo;
    int t = threadIdx.x;
    int v = (t < NBLK) ? bsum[t] : 0;
    s[t] = v;
    __syncthreads();
    for (int off = 1; off < 256; off <<= 1) {
        int u = (t >= off) ? s[t - off] : 0;
        __syncthreads();
        s[t] += u;
        __syncthreads();
    }
    if (t == 0) bo = s[blockIdx.x] - bsum[blockIdx.x];   // exclusive offset
    __syncthreads();
    int i = blockIdx.x * 256 + t;
    if (i < NNODES) row_start[i] = bo + excl[i];
    if (i == 0) row_start[NNODES] = NEDGES;
}

// ---------------- scatter edges into u16 CSR (no atomics) ----------------
__global__ void k_scatter(const u16* __restrict__ src16,
                          const unsigned int* __restrict__ drpack,
                          const int* __restrict__ row_start,
                          u16* __restrict__ csr16) {
    int e = blockIdx.x * blockDim.x + threadIdx.x;
    if (e >= NEDGES) return;
    unsigned int dp = drpack[e];
    int d = (int)(dp & 0xFFFFu);
    int r = (int)(dp >> 16);
    csr16[row_start[d] + r] = src16[e];
}

// ---- gather helpers: lane l covers dims 2l,2l+1 (u16 = 2 fp8) ----
__device__ __forceinline__ void g8(const u16* __restrict__ x8u, int my, int j,
                                   int l, float& a0, float& a1) {
    int i0 = __shfl(my, j + 0), i1 = __shfl(my, j + 1);
    int i2 = __shfl(my, j + 2), i3 = __shfl(my, j + 3);
    int i4 = __shfl(my, j + 4), i5 = __shfl(my, j + 5);
    int i6 = __shfl(my, j + 6), i7 = __shfl(my, j + 7);
    unsigned int u0 = x8u[((unsigned)i0 << 6) + l];
    unsigned int u1 = x8u[((unsigned)i1 << 6) + l];
    unsigned int u2 = x8u[((unsigned)i2 << 6) + l];
    unsigned int u3 = x8u[((unsigned)i3 << 6) + l];
    unsigned int u4 = x8u[((unsigned)i4 << 6) + l];
    unsigned int u5 = x8u[((unsigned)i5 << 6) + l];
    unsigned int u6 = x8u[((unsigned)i6 << 6) + l];
    unsigned int u7 = x8u[((unsigned)i7 << 6) + l];
    floatx2 v0 = __builtin_amdgcn_cvt_pk_f32_fp8(u0, false);
    floatx2 v1 = __builtin_amdgcn_cvt_pk_f32_fp8(u1, false);
    floatx2 v2 = __builtin_amdgcn_cvt_pk_f32_fp8(u2, false);
    floatx2 v3 = __builtin_amdgcn_cvt_pk_f32_fp8(u3, false);
    floatx2 v4 = __builtin_amdgcn_cvt_pk_f32_fp8(u4, false);
    floatx2 v5 = __builtin_amdgcn_cvt_pk_f32_fp8(u5, false);
    floatx2 v6 = __builtin_amdgcn_cvt_pk_f32_fp8(u6, false);
    floatx2 v7 = __builtin_amdgcn_cvt_pk_f32_fp8(u7, false);
    a0 += v0.x + v1.x + v2.x + v3.x + v4.x + v5.x + v6.x + v7.x;
    a1 += v0.y + v1.y + v2.y + v3.y + v4.y + v5.y + v6.y + v7.y;
}
__device__ __forceinline__ void g1(const u16* __restrict__ x8u, int my, int j,
                                   int l, float& a0, float& a1) {
    int si = __shfl(my, j);
    unsigned int u = x8u[((unsigned)si << 6) + l];
    floatx2 v = __builtin_amdgcn_cvt_pk_f32_fp8(u, false);
    a0 += v.x; a1 += v.y;
}

// -------- fused: fp8 CSR mean-gather (LDS) + MFMA layer1 + pre-transforms --
// 16 nodes/block, 8 waves (512 thr): wave w gathers nodes w*2, w*2+1 with the
// two chains JAMMED: per iteration, 8 loads for node a AND 8 for node b are
// issued before either accumulates -> 16 loads in flight (2x MLP vs serial
// chains, which was the R2 bottleneck: VALU 27%, all pipes idle).
// Phase 2 (MFMA):
//   H  = relu(mean @ W1_l + b1 + x @ W1_r)   [16 x 128] — wave w owns col-tile w
//   H2 = H @ W2_l                             [16 x 64]  -> h28 (fp8, waves 0-3)
//   HR = H @ W2_r + b2                        [16 x 64]  -> hrf (f32, waves 0-3)
__global__ __launch_bounds__(512) void k_l1fused(
        const int* __restrict__ row_start, const u16* __restrict__ csr16,
        const void* __restrict__ x, const u16* __restrict__ x8u,
        const int* __restrict__ flags,
        const bf16* __restrict__ p1l, const bf16* __restrict__ p1r,
        const bf16* __restrict__ p2l, const bf16* __restrict__ p2r,
        const void* __restrict__ b1, const void* __restrict__ b2v,
        u8* __restrict__ h28, float* __restrict__ hrf) {
    __shared__ bf16 ms[16][136];   // +8 pad -> 2-way-free LDS banking
    __shared__ bf16 xs[16][136];   // staged x rows (bf16)
    __shared__ bf16 hs[16][136];
    __shared__ u8 h2s8[16][72];    // 72 = 8*9: rows stay 8B-aligned
    __shared__ float hrs[16][68];
    int t = threadIdx.x;
    int w = t >> 6;    // 0..7
    int l = t & 63;
    int nb = blockIdx.x * 16;
    int isf32 = flags[1];
    int r0 = w * 2, r1 = r0 + 1;

    // 3 row_start values per wave, one coop load + shfl
    int rsv = row_start[nb + r0 + min(l, 2)];
    int s0 = __shfl(rsv, 0), s1 = __shfl(rsv, 1), s2 = __shfl(rsv, 2);

    // prefetch both nodes' first index chunks (pays idx latency once)
    int ca = min(64, s1 - s0);
    int cb = min(64, s2 - s1);
    int mya = (l < ca) ? (int)csr16[s0 + l] : 0;
    int myb = (l < cb) ? (int)csr16[s1 + l] : 0;

    // stage this wave's two x rows into LDS as bf16 (dims 2l, 2l+1)
    {
        long long ro0 = (long long)(nb + r0) * D_IN + 2 * l;
        long long ro1 = (long long)(nb + r1) * D_IN + 2 * l;
        unsigned int px0, px1;
        if (isf32) {
            float2 v0 = *(const float2*)((const float*)x + ro0);
            float2 v1 = *(const float2*)((const float*)x + ro1);
            px0 = ((unsigned int)f2bfbits(v0.y) << 16) | f2bfbits(v0.x);
            px1 = ((unsigned int)f2bfbits(v1.y) << 16) | f2bfbits(v1.x);
        } else {
            px0 = *(const unsigned int*)((const bf16*)x + ro0);
            px1 = *(const unsigned int*)((const bf16*)x + ro1);
        }
        *(unsigned int*)((bf16*)&xs[r0][0] + 2 * l) = px0;
        *(unsigned int*)((bf16*)&xs[r1][0] + 2 * l) = px1;
    }

    // ---- phase 1: fp8 gather, dual-chain jammed for max MLP
    float aa0 = 0.f, aa1 = 0.f;
    float bb0 = 0.f, bb1 = 0.f;
    {
        int mn = min(ca, cb);
        int j = 0;
        for (; j + 7 < mn; j += 8) {
            g8(x8u, mya, j, l, aa0, aa1);   // inlined: compiler clusters the
            g8(x8u, myb, j, l, bb0, bb1);   // 16 independent loads together
        }
        int ja = j;
        for (; ja + 7 < ca; ja += 8) g8(x8u, mya, ja, l, aa0, aa1);
        for (; ja < ca; ja++)        g1(x8u, mya, ja, l, aa0, aa1);
        int jb = j;
        for (; jb + 7 < cb; jb += 8) g8(x8u, myb, jb, l, bb0, bb1);
        for (; jb < cb; jb++)        g1(x8u, myb, jb, l, bb0, bb1);
    }
    for (int base = s0 + 64; base < s1; base += 64) {   // rare deg>64 tail
        int cnt2 = min(64, s1 - base);
        int my = (l < cnt2) ? (int)csr16[base + l] : 0;
        int j = 0;
        for (; j + 7 < cnt2; j += 8) g8(x8u, my, j, l, aa0, aa1);
        for (; j < cnt2; j++)        g1(x8u, my, j, l, aa0, aa1);
    }
    for (int base = s1 + 64; base < s2; base += 64) {
        int cnt2 = min(64, s2 - base);
        int my = (l < cnt2) ? (int)csr16[base + l] : 0;
        int j = 0;
        for (; j + 7 < cnt2; j += 8) g8(x8u, my, j, l, bb0, bb1);
        for (; j < cnt2; j++)        g1(x8u, my, j, l, bb0, bb1);
    }
    {
        float inv = 1.0f / fmaxf((float)(s1 - s0), 1.0f);
        unsigned int pk = ((unsigned int)f2bfbits(aa1 * inv) << 16) | f2bfbits(aa0 * inv);
        *(unsigned int*)((bf16*)&ms[r0][0] + 2 * l) = pk;
    }
    {
        float inv = 1.0f / fmaxf((float)(s2 - s1), 1.0f);
        unsigned int pk = ((unsigned int)f2bfbits(bb1 * inv) << 16) | f2bfbits(bb0 * inv);
        *(unsigned int*)((bf16*)&ms[r1][0] + 2 * l) = pk;
    }
    __syncthreads();

    // ---- phase 2: MFMA — wave w owns layer-1 column tile nt = w
    int m = l & 15;
    int quad = l >> 4;
    floatx4 acc0 = {0.f, 0.f, 0.f, 0.f};
    #pragma unroll
    for (int kt = 0; kt < 4; kt++) {
        short8 amv = *(const short8*)&ms[m][kt * 32 + quad * 8];
        short8 axv = *(const short8*)&xs[m][kt * 32 + quad * 8];
        short8 bl0 = *(const short8*)(p1l + (((w * 4 + kt) * 64 + l) * 8));
        short8 br0 = *(const short8*)(p1r + (((w * 4 + kt) * 64 + l) * 8));
        acc0 = __builtin_amdgcn_mfma_f32_16x16x32_bf16(amv, bl0, acc0, 0, 0, 0);
        acc0 = __builtin_amdgcn_mfma_f32_16x16x32_bf16(axv, br0, acc0, 0, 0, 0);
    }
    int c0 = w * 16 + m;
    float bias0 = ld(b1, c0, isf32);
    #pragma unroll
    for (int r = 0; r < 4; r++) {
        hs[quad * 4 + r][c0] = __float2bfloat16(fmaxf(acc0[r] + bias0, 0.f));
    }
    __syncthreads();
    if (w < 4) {       // layer 2: 4 waves cover the 64 output cols
        floatx4 acc2 = {0.f, 0.f, 0.f, 0.f};
        floatx4 acc3 = {0.f, 0.f, 0.f, 0.f};
        #pragma unroll
        for (int kt = 0; kt < 4; kt++) {
            short8 ah = *(const short8*)&hs[m][kt * 32 + quad * 8];
            short8 bw = *(const short8*)(p2l + (((w * 4 + kt) * 64 + l) * 8));
            short8 bz = *(const short8*)(p2r + (((w * 4 + kt) * 64 + l) * 8));
            acc2 = __builtin_amdgcn_mfma_f32_16x16x32_bf16(ah, bw, acc2, 0, 0, 0);
            acc3 = __builtin_amdgcn_mfma_f32_16x16x32_bf16(ah, bz, acc3, 0, 0, 0);
        }
        int c2 = w * 16 + m;
        float bias2 = ld(b2v, c2, isf32);
        #pragma unroll
        for (int r = 0; r < 4; r++) {
            h2s8[quad * 4 + r][c2] = f2fp8(acc2[r]);      // f32 -> fp8 direct
            hrs[quad * 4 + r][c2] = acc3[r] + bias2;
        }
    }
    __syncthreads();
    if (t < 128) {
        int node = t >> 3, col0 = (t & 7) * 8;
        uint2 v = *(const uint2*)&h2s8[node][col0];
        *(uint2*)(h28 + (long long)(nb + node) * D_OUT + col0) = v;
    }
    if (t < 256) {
        int node = t >> 4, col0 = (t & 15) * 4;
        float4 v = *(const float4*)&hrs[node][col0];
        *(float4*)(hrf + (long long)(nb + node) * D_OUT + col0) = v;
    }
}

// ---- agg2 helpers: quarter-wave per row, lane covers dims 4c..4c+3 ----
__device__ __forceinline__ void a16(const unsigned int* __restrict__ h32, int my,
                                    int j, int g, int c,
                                    float& a0, float& a1, float& a2, float& a3) {
    int i0 = __shfl(my, j + g);
    int i1 = __shfl(my, j + 4 + g);
    int i2 = __shfl(my, j + 8 + g);
    int i3 = __shfl(my, j + 12 + g);
    unsigned int u0 = h32[(size_t)i0 * 16 + c];
    unsigned int u1 = h32[(size_t)i1 * 16 + c];
    unsigned int u2 = h32[(size_t)i2 * 16 + c];
    unsigned int u3 = h32[(size_t)i3 * 16 + c];
    floatx2 l0 = __builtin_amdgcn_cvt_pk_f32_fp8(u0, false);
    floatx2 h0 = __builtin_amdgcn_cvt_pk_f32_fp8(u0, true);
    floatx2 l1 = __builtin_amdgcn_cvt_pk_f32_fp8(u1, false);
    floatx2 h1 = __builtin_amdgcn_cvt_pk_f32_fp8(u1, true);
    floatx2 l2 = __builtin_amdgcn_cvt_pk_f32_fp8(u2, false);
    floatx2 h2 = __builtin_amdgcn_cvt_pk_f32_fp8(u2, true);
    floatx2 l3 = __builtin_amdgcn_cvt_pk_f32_fp8(u3, false);
    floatx2 h3 = __builtin_amdgcn_cvt_pk_f32_fp8(u3, true);
    a0 += l0.x + l1.x + l2.x + l3.x;
    a1 += l0.y + l1.y + l2.y + l3.y;
    a2 += h0.x + h1.x + h2.x + h3.x;
    a3 += h0.y + h1.y + h2.y + h3.y;
}
__device__ __forceinline__ void atail(const unsigned int* __restrict__ h32, int my,
                                      int j, int cnt2, int g, int c,
                                      float& a0, float& a1, float& a2, float& a3) {
    for (; j + 7 < cnt2; j += 8) {            // 2 loads -> 8 neighbors
        int i0 = __shfl(my, j + g);
        int i1 = __shfl(my, j + 4 + g);
        unsigned int u0 = h32[(size_t)i0 * 16 + c];
        unsigned int u1 = h32[(size_t)i1 * 16 + c];
        floatx2 l0 = __builtin_amdgcn_cvt_pk_f32_fp8(u0, false);
        floatx2 h0 = __builtin_amdgcn_cvt_pk_f32_fp8(u0, true);
        floatx2 l1 = __builtin_amdgcn_cvt_pk_f32_fp8(u1, false);
        floatx2 h1 = __builtin_amdgcn_cvt_pk_f32_fp8(u1, true);
        a0 += l0.x + l1.x; a1 += l0.y + l1.y;
        a2 += h0.x + h1.x; a3 += h0.y + h1.y;
    }
    for (; j < cnt2; j += 4) {                // predicated tail (<=3 iters)
        int jj = j + g;
        float mk = (jj < cnt2) ? 1.0f : 0.0f;
        int i0 = __shfl(my, jj & 63);
        unsigned int u0 = h32[(size_t)i0 * 16 + c];
        floatx2 l0 = __builtin_amdgcn_cvt_pk_f32_fp8(u0, false);
        floatx2 h0 = __builtin_amdgcn_cvt_pk_f32_fp8(u0, true);
        a0 += mk * l0.x; a1 += mk * l0.y;
        a2 += mk * h0.x; a3 += mk * h0.y;
    }
}

// ---------------- layer-2 aggregation + add hr ----------------------------
// 2 nodes per wave, chains jammed (8 u32 loads in flight vs 4). Quarter-wave
// per row: groups g=0..3 take 4 neighbors/iteration, lane covers dims
// 4c..4c+3. Two-stage shfl_xor reduce; lanes<16 write each node's float4.
__global__ void k_agg2g(const int* __restrict__ row_start, const u16* __restrict__ csr16,
                        const u8* __restrict__ h28, const float* __restrict__ hrf,
                        const int* __restrict__ flags, void* __restrict__ out) {
    int t = threadIdx.x;
    int lane = t & 63;
    int n0 = blockIdx.x * 8 + (t >> 6) * 2;
    int n1 = n0 + 1;
    int g = lane >> 4;   // neighbor group 0..3
    int c = lane & 15;   // u32 column -> dims 4c..4c+3
    const unsigned int* h32 = (const unsigned int*)h28;

    int rsv = row_start[n0 + min(lane, 2)];
    int s0 = __shfl(rsv, 0), s1 = __shfl(rsv, 1), s2 = __shfl(rsv, 2);
    int ca = min(64, s1 - s0);
    int cb = min(64, s2 - s1);
    int mya = (lane < ca) ? (int)csr16[s0 + lane] : 0;
    int myb = (lane < cb) ? (int)csr16[s1 + lane] : 0;

    float a0 = 0.f, a1 = 0.f, a2 = 0.f, a3 = 0.f;
    float b0 = 0.f, b1 = 0.f, b2 = 0.f, b3 = 0.f;
    {
        int mn = min(ca, cb);
        int j = 0;
        for (; j + 15 < mn; j += 16) {
            a16(h32, mya, j, g, c, a0, a1, a2, a3);   // 8 independent loads
            a16(h32, myb, j, g, c, b0, b1, b2, b3);   // clustered by scheduler
        }
        int ja = j;
        for (; ja + 15 < ca; ja += 16) a16(h32, mya, ja, g, c, a0, a1, a2, a3);
        atail(h32, mya, ja, ca, g, c, a0, a1, a2, a3);
        int jb = j;
        for (; jb + 15 < cb; jb += 16) a16(h32, myb, jb, g, c, b0, b1, b2, b3);
        atail(h32, myb, jb, cb, g, c, b0, b1, b2, b3);
    }
    for (int base = s0 + 64; base < s1; base += 64) {   // rare deg>64 tail
        int cnt2 = min(64, s1 - base);
        int my = (lane < cnt2) ? (int)csr16[base + lane] : 0;
        int j = 0;
        for (; j + 15 < cnt2; j += 16) a16(h32, my, j, g, c, a0, a1, a2, a3);
        atail(h32, my, j, cnt2, g, c, a0, a1, a2, a3);
    }
    for (int base = s1 + 64; base < s2; base += 64) {
        int cnt2 = min(64, s2 - base);
        int my = (lane < cnt2) ? (int)csr16[base + lane] : 0;
        int j = 0;
        for (; j + 15 < cnt2; j += 16) a16(h32, my, j, g, c, b0, b1, b2, b3);
        atail(h32, my, j, cnt2, g, c, b0, b1, b2, b3);
    }
    a0 += __shfl_xor(a0, 32); a0 += __shfl_xor(a0, 16);
    a1 += __shfl_xor(a1, 32); a1 += __shfl_xor(a1, 16);
    a2 += __shfl_xor(a2, 32); a2 += __shfl_xor(a2, 16);
    a3 += __shfl_xor(a3, 32); a3 += __shfl_xor(a3, 16);
    b0 += __shfl_xor(b0, 32); b0 += __shfl_xor(b0, 16);
    b1 += __shfl_xor(b1, 32); b1 += __shfl_xor(b1, 16);
    b2 += __shfl_xor(b2, 32); b2 += __shfl_xor(b2, 16);
    b3 += __shfl_xor(b3, 32); b3 += __shfl_xor(b3, 16);
    if (lane < 16) {
        float inv = 1.0f / fmaxf((float)(s1 - s0), 1.0f);
        const float4 hr = *(const float4*)&hrf[(size_t)n0 * D_OUT + (c << 2)];
        float o0 = a0 * inv + hr.x;
        float o1 = a1 * inv + hr.y;
        float o2 = a2 * inv + hr.z;
        float o3 = a3 * inv + hr.w;
        if (flags[1]) {
            float4 v = {o0, o1, o2, o3};
            *(float4*)((float*)out + (size_t)n0 * D_OUT + (c << 2)) = v;
        } else {
            uint2 v;
            v.x = ((unsigned int)f2bfbits(o1) << 16) | f2bfbits(o0);
            v.y = ((unsigned int)f2bfbits(o3) << 16) | f2bfbits(o2);
            *(uint2*)((bf16*)out + (size_t)n0 * D_OUT + (c << 2)) = v;
        }
    } else if (lane < 32) {
        float inv = 1.0f / fmaxf((float)(s2 - s1), 1.0f);
        const float4 hr = *(const float4*)&hrf[(size_t)n1 * D_OUT + (c << 2)];
        float o0 = b0 * inv + hr.x;
        float o1 = b1 * inv + hr.y;
        float o2 = b2 * inv + hr.z;
        float o3 = b3 * inv + hr.w;
        if (flags[1]) {
            float4 v = {o0, o1, o2, o3};
            *(float4*)((float*)out + (size_t)n1 * D_OUT + (c << 2)) = v;
        } else {
            uint2 v;
            v.x = ((unsigned int)f2bfbits(o1) << 16) | f2bfbits(o0);
            v.y = ((unsigned int)f2bfbits(o3) << 16) | f2bfbits(o2);
            *(uint2*)((bf16*)out + (size_t)n1 * D_OUT + (c << 2)) = v;
        }
    }
}

extern "C" void kernel_launch(void* const* d_in, const int* in_sizes, int n_in,
                              void* d_out, int out_size, void* d_ws, size_t ws_size,
                              hipStream_t stream) {
    const void* x   = d_in[0];
    const int*  ei  = (const int*)d_in[1];
    const void* W1l = d_in[2];
    const void* b1  = d_in[3];
    const void* W1r = d_in[4];
    const void* W2l = d_in[5];
    const void* b2v = d_in[6];
    const void* W2r = d_in[7];

    const int N = NNODES;
    const int E = NEDGES;

    // ws layout (int units; large arrays 16B-aligned):
    int*          flags     = (int*)d_ws;
    u16*          src16     = (u16*)(flags + 4);            // E u16
    unsigned int* drpack    = (unsigned int*)(src16 + E);   // E u32
    int*          cnt       = (int*)(drpack + E);           // N
    int*          excl      = cnt + N;
    int*          bsum      = excl + N;
    int*          row_start = bsum + 256;                   // N+16
    u16*          csr16     = (u16*)(row_start + (N + 16)); // E u16
    bf16*         p1l       = (bf16*)(csr16 + E);           // 16384 bf16
    bf16*         p1r       = p1l + 16384;
    bf16*         p2l       = p1r + 16384;                  // 8192 bf16
    bf16*         p2r       = p2l + 8192;                   // 8192 bf16
    unsigned int* x8        = (unsigned int*)(p2r + 8192);  // N*128/4 u32
    u8*           h28       = (u8*)(x8 + (size_t)N * D_IN / 4);   // N*64 fp8
    float*        hrf       = (float*)(h28 + (size_t)N * D_OUT);  // N*64 f32

    k_setup<<<152 + 1024, 256, 0, stream>>>(cnt, N, (const unsigned int*)ei,
                                            (const unsigned int*)W1l, flags, x,
                                            W1l, W1r, W2l, W2r,
                                            p1l, p1r, p2l, p2r, x8);
    k_edges<<<(E + 255) / 256, 256, 0, stream>>>(ei, flags, src16, drpack, cnt);
    k_scan_a<<<NBLK, 256, 0, stream>>>(cnt, excl, bsum);
    k_scan_bc<<<NBLK, 256, 0, stream>>>(excl, bsum, row_start);
    k_scatter<<<(E + 255) / 256, 256, 0, stream>>>(src16, drpack, row_start, csr16);
    k_l1fused<<<N / 16, 512, 0, stream>>>(row_start, csr16, x, (const u16*)x8, flags,
                                          p1l, p1r, p2l, p2r, b1, b2v, h28, hrf);
    k_agg2g<<<N / 8, 256, 0, stream>>>(row_start, csr16, h28, hrf, flags, d_out);
}

// Round 4
// 196.648 us; speedup vs baseline: 1.1164x; 1.0212x over previous
//
#include <hip/hip_runtime.h>
#include <hip/hip_bf16.h>

typedef __hip_bfloat16 bf16;
typedef __attribute__((ext_vector_type(8))) short short8;
typedef __attribute__((ext_vector_type(4))) float floatx4;
typedef __attribute__((ext_vector_type(2))) float floatx2;
typedef unsigned short u16;
typedef unsigned char u8;

#define NNODES 50000
#define NEDGES 800000
#define D_IN  128
#define D_HID 128
#define D_OUT 64
#define NBLK  ((NNODES + 255) / 256)   // 196 scan blocks

__device__ __forceinline__ float bfbits2f(unsigned int u) {
    return __uint_as_float(u << 16);
}
__device__ __forceinline__ float b2f(bf16 v) { return __bfloat162float(v); }
__device__ __forceinline__ unsigned short f2bfbits(float f) {
    bf16 b = __float2bfloat16(f);
    return *(unsigned short*)&b;
}
__device__ __forceinline__ u8 f2fp8(float f) {
    return (u8)(__builtin_amdgcn_cvt_pk_fp8_f32(f, 0.f, 0, false) & 0xFF);
}
__device__ __forceinline__ float ld(const void* p, long long idx, int isf32) {
    if (isf32) return ((const float*)p)[idx];
    return b2f(((const bf16*)p)[idx]);
}

// ---- setup: zero cnt + detect (blocks 0..127), pack W (128..151),
//      build fp8 x-table (152..) -----------------------------------------
// flags[0] = 1 if edge_index is int64; flags[1] = 1 if float arrays are f32
__global__ void k_setup(int* __restrict__ cnt, int n,
                        const unsigned int* __restrict__ ei_words,
                        const unsigned int* __restrict__ w_words,
                        int* __restrict__ flags,
                        const void* __restrict__ x,
                        const void* __restrict__ W1l, const void* __restrict__ W1r,
                        const void* __restrict__ W2l, const void* __restrict__ W2r,
                        bf16* __restrict__ p1l, bf16* __restrict__ p1r,
                        bf16* __restrict__ p2l, bf16* __restrict__ p2r,
                        unsigned int* __restrict__ x8) {
    int b = blockIdx.x;
    if (b < 128) {
        if (b == 0) {
            __shared__ int cnt_zero, cnt_bf;
            if (threadIdx.x == 0) { cnt_zero = 0; cnt_bf = 0; }
            __syncthreads();
            int t = threadIdx.x;
            unsigned int we = ei_words[2 * t + 1];
            if (we == 0u) atomicAdd(&cnt_zero, 1);
            unsigned int ww = w_words[t];
            unsigned int lowexp = (ww >> 7) & 0xFFu;
            if (lowexp >= 0x60u && lowexp <= 0x7Bu) atomicAdd(&cnt_bf, 1);
            __syncthreads();
            if (threadIdx.x == 0) {
                flags[0] = (cnt_zero >= 240) ? 1 : 0;
                flags[1] = (cnt_bf >= 192) ? 0 : 1;
            }
        }
        int i = b * blockDim.x + threadIdx.x;
        int stride = 128 * blockDim.x;
        for (; i < n; i += stride) cnt[i] = 0;
        return;
    }
    // local dtype detection (flags not yet visible grid-wide)
    __shared__ int cnt_bf2;
    if (threadIdx.x == 0) cnt_bf2 = 0;
    __syncthreads();
    {
        unsigned int ww = w_words[threadIdx.x];
        unsigned int lowexp = (ww >> 7) & 0xFFu;
        if (lowexp >= 0x60u && lowexp <= 0x7Bu) atomicAdd(&cnt_bf2, 1);
    }
    __syncthreads();
    int isf32 = (cnt_bf2 >= 192) ? 0 : 1;
    if (b < 152) {  // ---- weight pack into MFMA B-fragment order
        int t = (b - 128) * 256 + threadIdx.x;
        if (t >= 6144) return;
        const void* Wm; bf16* dst; int NT; int base;
        if (t < 2048)      { Wm = W1l; dst = p1l; NT = 8; base = t; }
        else if (t < 4096) { Wm = W1r; dst = p1r; NT = 8; base = t - 2048; }
        else if (t < 5120) { Wm = W2l; dst = p2l; NT = 4; base = t - 4096; }
        else               { Wm = W2r; dst = p2r; NT = 4; base = t - 5120; }
        int lane = base & 63;
        int kt = (base >> 6) & 3;
        int nt = base >> 8;
        int Nmat = NT * 16;
        int krow = kt * 32 + ((lane >> 4) * 8);
        int col = nt * 16 + (lane & 15);
        #pragma unroll
        for (int j = 0; j < 8; j++) {
            float v = ld(Wm, (long long)(krow + j) * Nmat + col, isf32);
            dst[(((nt * 4 + kt) * 64 + lane) * 8) + j] = __float2bfloat16(v);
        }
        return;
    }
    // ---- fp8 (e4m3) x-table: 4 elems -> 1 u32 per thread, grid-stride
    const long long NU32 = (long long)NNODES * D_IN / 4;  // 1.6M
    long long i = (long long)(b - 152) * 256 + threadIdx.x;
    long long stride = (long long)(gridDim.x - 152) * 256;
    if (isf32) {
        const float4* xf = (const float4*)x;
        for (; i < NU32; i += stride) {
            float4 f = xf[i];
            unsigned int w0 = __builtin_amdgcn_cvt_pk_fp8_f32(f.x, f.y, 0, false);
            w0 = __builtin_amdgcn_cvt_pk_fp8_f32(f.z, f.w, w0, true);
            x8[i] = w0;
        }
    } else {
        const ushort4* xb = (const ushort4*)x;
        for (; i < NU32; i += stride) {
            ushort4 s = xb[i];
            float f0 = bfbits2f(s.x), f1 = bfbits2f(s.y);
            float f2 = bfbits2f(s.z), f3 = bfbits2f(s.w);
            unsigned int w0 = __builtin_amdgcn_cvt_pk_fp8_f32(f0, f1, 0, false);
            w0 = __builtin_amdgcn_cvt_pk_fp8_f32(f2, f3, w0, true);
            x8[i] = w0;
        }
    }
}

// ------- edges: canonicalize + histogram + per-edge rank (packed w/ dst) ----
// drpack[e] = (rank << 16) | dst   (both < 65536)
__global__ void k_edges(const int* __restrict__ ei, const int* __restrict__ flags,
                        u16* __restrict__ src16, unsigned int* __restrict__ drpack,
                        int* __restrict__ cnt) {
    int e = blockIdx.x * blockDim.x + threadIdx.x;
    if (e >= NEDGES) return;
    int s, d;
    if (flags[0]) { s = ei[2 * e]; d = ei[2 * (NEDGES + e)]; }
    else          { s = ei[e];     d = ei[NEDGES + e]; }
    src16[e] = (u16)s;
    int rank = atomicAdd(&cnt[d], 1);
    drpack[e] = ((unsigned int)rank << 16) | (unsigned int)d;
}

// ---------------- 2-phase exclusive scan ----------------
__global__ void k_scan_a(const int* __restrict__ cnt, int* __restrict__ excl,
                         int* __restrict__ bsum) {
    __shared__ int s[256];
    int t = threadIdx.x;
    int i = blockIdx.x * 256 + t;
    int v = (i < NNODES) ? cnt[i] : 0;
    s[t] = v;
    __syncthreads();
    for (int off = 1; off < 256; off <<= 1) {
        int u = (t >= off) ? s[t - off] : 0;
        __syncthreads();
        s[t] += u;
        __syncthreads();
    }
    if (i < NNODES) excl[i] = s[t] - v;
    if (t == 255) bsum[blockIdx.x] = s[255];
}

// every block scans bsum in LDS (redundant but cheap), picks its offset,
// then writes row_start — merges old scan_b+scan_c into one launch
__global__ void k_scan_bc(const int* __restrict__ excl, const int* __restrict__ bsum,
                          int* __restrict__ row_start) {
    __shared__ int s[256];
    __shared__ int bo;
    int t = threadIdx.x;
    int v = (t < NBLK) ? bsum[t] : 0;
    s[t] = v;
    __syncthreads();
    for (int off = 1; off < 256; off <<= 1) {
        int u = (t >= off) ? s[t - off] : 0;
        __syncthreads();
        s[t] += u;
        __syncthreads();
    }
    if (t == 0) bo = s[blockIdx.x] - bsum[blockIdx.x];   // exclusive offset
    __syncthreads();
    int i = blockIdx.x * 256 + t;
    if (i < NNODES) row_start[i] = bo + excl[i];
    if (i == 0) row_start[NNODES] = NEDGES;
}

// ---------------- scatter edges into u16 CSR (no atomics) ----------------
__global__ void k_scatter(const u16* __restrict__ src16,
                          const unsigned int* __restrict__ drpack,
                          const int* __restrict__ row_start,
                          u16* __restrict__ csr16) {
    int e = blockIdx.x * blockDim.x + threadIdx.x;
    if (e >= NEDGES) return;
    unsigned int dp = drpack[e];
    int d = (int)(dp & 0xFFFFu);
    int r = (int)(dp >> 16);
    csr16[row_start[d] + r] = src16[e];
}

// ---- masked 8-wide gather round: lane l covers dims 2l,2l+1 --------------
// All 8 loads issue in parallel; neighbors >= cnt2 contribute 0 (their lanes
// hold index 0, so the loads are safe). This removes the serial scalar-tail
// loop that dominated R2/R3 (each tail neighbor was a dependent ~600cy chain).
__device__ __forceinline__ void g8m(const u16* __restrict__ x8u, int my, int j,
                                    int cnt2, int l, float& a0, float& a1) {
    int i0 = __shfl(my, j + 0), i1 = __shfl(my, j + 1);
    int i2 = __shfl(my, j + 2), i3 = __shfl(my, j + 3);
    int i4 = __shfl(my, j + 4), i5 = __shfl(my, j + 5);
    int i6 = __shfl(my, j + 6), i7 = __shfl(my, j + 7);
    unsigned int u0 = x8u[((unsigned)i0 << 6) + l];
    unsigned int u1 = x8u[((unsigned)i1 << 6) + l];
    unsigned int u2 = x8u[((unsigned)i2 << 6) + l];
    unsigned int u3 = x8u[((unsigned)i3 << 6) + l];
    unsigned int u4 = x8u[((unsigned)i4 << 6) + l];
    unsigned int u5 = x8u[((unsigned)i5 << 6) + l];
    unsigned int u6 = x8u[((unsigned)i6 << 6) + l];
    unsigned int u7 = x8u[((unsigned)i7 << 6) + l];
    float m0 = (j + 0 < cnt2) ? 1.f : 0.f;
    float m1 = (j + 1 < cnt2) ? 1.f : 0.f;
    float m2 = (j + 2 < cnt2) ? 1.f : 0.f;
    float m3 = (j + 3 < cnt2) ? 1.f : 0.f;
    float m4 = (j + 4 < cnt2) ? 1.f : 0.f;
    float m5 = (j + 5 < cnt2) ? 1.f : 0.f;
    float m6 = (j + 6 < cnt2) ? 1.f : 0.f;
    float m7 = (j + 7 < cnt2) ? 1.f : 0.f;
    floatx2 v0 = __builtin_amdgcn_cvt_pk_f32_fp8(u0, false);
    floatx2 v1 = __builtin_amdgcn_cvt_pk_f32_fp8(u1, false);
    floatx2 v2 = __builtin_amdgcn_cvt_pk_f32_fp8(u2, false);
    floatx2 v3 = __builtin_amdgcn_cvt_pk_f32_fp8(u3, false);
    floatx2 v4 = __builtin_amdgcn_cvt_pk_f32_fp8(u4, false);
    floatx2 v5 = __builtin_amdgcn_cvt_pk_f32_fp8(u5, false);
    floatx2 v6 = __builtin_amdgcn_cvt_pk_f32_fp8(u6, false);
    floatx2 v7 = __builtin_amdgcn_cvt_pk_f32_fp8(u7, false);
    a0 += m0 * v0.x; a1 += m0 * v0.y;
    a0 += m1 * v1.x; a1 += m1 * v1.y;
    a0 += m2 * v2.x; a1 += m2 * v2.y;
    a0 += m3 * v3.x; a1 += m3 * v3.y;
    a0 += m4 * v4.x; a1 += m4 * v4.y;
    a0 += m5 * v5.x; a1 += m5 * v5.y;
    a0 += m6 * v6.x; a1 += m6 * v6.y;
    a0 += m7 * v7.x; a1 += m7 * v7.y;
}

// -------- fused: fp8 CSR mean-gather (LDS) + MFMA layer1 + pre-transforms --
// 16 nodes/block, 8 waves (512 thr): wave w gathers nodes w*2, w*2+1; rounds
// are masked g8m (no scalar tails) and the two nodes' rounds are jammed so
// up to 16 loads are in flight.
// Phase 2 (MFMA):
//   H  = relu(mean @ W1_l + b1 + x @ W1_r)   [16 x 128] — wave w owns col-tile w
//   H2 = H @ W2_l                             [16 x 64]  -> h28 (fp8, waves 0-3)
//   HR = H @ W2_r + b2                        [16 x 64]  -> hrf (f32, waves 0-3)
__global__ __launch_bounds__(512) void k_l1fused(
        const int* __restrict__ row_start, const u16* __restrict__ csr16,
        const void* __restrict__ x, const u16* __restrict__ x8u,
        const int* __restrict__ flags,
        const bf16* __restrict__ p1l, const bf16* __restrict__ p1r,
        const bf16* __restrict__ p2l, const bf16* __restrict__ p2r,
        const void* __restrict__ b1, const void* __restrict__ b2v,
        u8* __restrict__ h28, float* __restrict__ hrf) {
    __shared__ bf16 ms[16][136];   // +8 pad -> 2-way-free LDS banking
    __shared__ bf16 xs[16][136];   // staged x rows (bf16)
    __shared__ bf16 hs[16][136];
    __shared__ u8 h2s8[16][72];    // 72 = 8*9: rows stay 8B-aligned
    __shared__ float hrs[16][68];
    int t = threadIdx.x;
    int w = t >> 6;    // 0..7
    int l = t & 63;
    int nb = blockIdx.x * 16;
    int isf32 = flags[1];
    int r0 = w * 2, r1 = r0 + 1;

    // 3 row_start values per wave, one coop load + shfl
    int rsv = row_start[nb + r0 + min(l, 2)];
    int s0 = __shfl(rsv, 0), s1 = __shfl(rsv, 1), s2 = __shfl(rsv, 2);

    // prefetch both nodes' first index chunks (pays idx latency once)
    int ca = min(64, s1 - s0);
    int cb = min(64, s2 - s1);
    int mya = (l < ca) ? (int)csr16[s0 + l] : 0;
    int myb = (l < cb) ? (int)csr16[s1 + l] : 0;

    // stage this wave's two x rows into LDS as bf16 (dims 2l, 2l+1)
    {
        long long ro0 = (long long)(nb + r0) * D_IN + 2 * l;
        long long ro1 = (long long)(nb + r1) * D_IN + 2 * l;
        unsigned int px0, px1;
        if (isf32) {
            float2 v0 = *(const float2*)((const float*)x + ro0);
            float2 v1 = *(const float2*)((const float*)x + ro1);
            px0 = ((unsigned int)f2bfbits(v0.y) << 16) | f2bfbits(v0.x);
            px1 = ((unsigned int)f2bfbits(v1.y) << 16) | f2bfbits(v1.x);
        } else {
            px0 = *(const unsigned int*)((const bf16*)x + ro0);
            px1 = *(const unsigned int*)((const bf16*)x + ro1);
        }
        *(unsigned int*)((bf16*)&xs[r0][0] + 2 * l) = px0;
        *(unsigned int*)((bf16*)&xs[r1][0] + 2 * l) = px1;
    }

    // ---- phase 1: fp8 gather — masked rounds, dual-chain jammed
    float aa0 = 0.f, aa1 = 0.f;
    float bb0 = 0.f, bb1 = 0.f;
    {
        int mx = max(ca, cb);
        for (int j = 0; j < mx; j += 8) {
            if (j < ca) g8m(x8u, mya, j, ca, l, aa0, aa1);
            if (j < cb) g8m(x8u, myb, j, cb, l, bb0, bb1);
        }
    }
    for (int base = s0 + 64; base < s1; base += 64) {   // rare deg>64 tail
        int cnt2 = min(64, s1 - base);
        int my = (l < cnt2) ? (int)csr16[base + l] : 0;
        for (int j = 0; j < cnt2; j += 8) g8m(x8u, my, j, cnt2, l, aa0, aa1);
    }
    for (int base = s1 + 64; base < s2; base += 64) {
        int cnt2 = min(64, s2 - base);
        int my = (l < cnt2) ? (int)csr16[base + l] : 0;
        for (int j = 0; j < cnt2; j += 8) g8m(x8u, my, j, cnt2, l, bb0, bb1);
    }
    {
        float inv = 1.0f / fmaxf((float)(s1 - s0), 1.0f);
        unsigned int pk = ((unsigned int)f2bfbits(aa1 * inv) << 16) | f2bfbits(aa0 * inv);
        *(unsigned int*)((bf16*)&ms[r0][0] + 2 * l) = pk;
    }
    {
        float inv = 1.0f / fmaxf((float)(s2 - s1), 1.0f);
        unsigned int pk = ((unsigned int)f2bfbits(bb1 * inv) << 16) | f2bfbits(bb0 * inv);
        *(unsigned int*)((bf16*)&ms[r1][0] + 2 * l) = pk;
    }
    __syncthreads();

    // ---- phase 2: MFMA — wave w owns layer-1 column tile nt = w
    int m = l & 15;
    int quad = l >> 4;
    floatx4 acc0 = {0.f, 0.f, 0.f, 0.f};
    #pragma unroll
    for (int kt = 0; kt < 4; kt++) {
        short8 amv = *(const short8*)&ms[m][kt * 32 + quad * 8];
        short8 axv = *(const short8*)&xs[m][kt * 32 + quad * 8];
        short8 bl0 = *(const short8*)(p1l + (((w * 4 + kt) * 64 + l) * 8));
        short8 br0 = *(const short8*)(p1r + (((w * 4 + kt) * 64 + l) * 8));
        acc0 = __builtin_amdgcn_mfma_f32_16x16x32_bf16(amv, bl0, acc0, 0, 0, 0);
        acc0 = __builtin_amdgcn_mfma_f32_16x16x32_bf16(axv, br0, acc0, 0, 0, 0);
    }
    int c0 = w * 16 + m;
    float bias0 = ld(b1, c0, isf32);
    #pragma unroll
    for (int r = 0; r < 4; r++) {
        hs[quad * 4 + r][c0] = __float2bfloat16(fmaxf(acc0[r] + bias0, 0.f));
    }
    __syncthreads();
    if (w < 4) {       // layer 2: 4 waves cover the 64 output cols
        floatx4 acc2 = {0.f, 0.f, 0.f, 0.f};
        floatx4 acc3 = {0.f, 0.f, 0.f, 0.f};
        #pragma unroll
        for (int kt = 0; kt < 4; kt++) {
            short8 ah = *(const short8*)&hs[m][kt * 32 + quad * 8];
            short8 bw = *(const short8*)(p2l + (((w * 4 + kt) * 64 + l) * 8));
            short8 bz = *(const short8*)(p2r + (((w * 4 + kt) * 64 + l) * 8));
            acc2 = __builtin_amdgcn_mfma_f32_16x16x32_bf16(ah, bw, acc2, 0, 0, 0);
            acc3 = __builtin_amdgcn_mfma_f32_16x16x32_bf16(ah, bz, acc3, 0, 0, 0);
        }
        int c2 = w * 16 + m;
        float bias2 = ld(b2v, c2, isf32);
        #pragma unroll
        for (int r = 0; r < 4; r++) {
            h2s8[quad * 4 + r][c2] = f2fp8(acc2[r]);      // f32 -> fp8 direct
            hrs[quad * 4 + r][c2] = acc3[r] + bias2;
        }
    }
    __syncthreads();
    if (t < 128) {
        int node = t >> 3, col0 = (t & 7) * 8;
        uint2 v = *(const uint2*)&h2s8[node][col0];
        *(uint2*)(h28 + (long long)(nb + node) * D_OUT + col0) = v;
    }
    if (t < 256) {
        int node = t >> 4, col0 = (t & 15) * 4;
        float4 v = *(const float4*)&hrs[node][col0];
        *(float4*)(hrf + (long long)(nb + node) * D_OUT + col0) = v;
    }
}

// ---- masked 16-wide agg2 round: quarter-wave per row, dims 4c..4c+3 ------
// 4 loads cover neighbors j..j+15; per-load mask zeroes OOB contributions.
__device__ __forceinline__ void a16m(const unsigned int* __restrict__ h32, int my,
                                     int j, int cnt2, int g, int c,
                                     float& a0, float& a1, float& a2, float& a3) {
    int jj0 = j + g, jj1 = j + 4 + g, jj2 = j + 8 + g, jj3 = j + 12 + g;
    int i0 = __shfl(my, jj0);
    int i1 = __shfl(my, jj1);
    int i2 = __shfl(my, jj2);
    int i3 = __shfl(my, jj3);
    unsigned int u0 = h32[(size_t)i0 * 16 + c];
    unsigned int u1 = h32[(size_t)i1 * 16 + c];
    unsigned int u2 = h32[(size_t)i2 * 16 + c];
    unsigned int u3 = h32[(size_t)i3 * 16 + c];
    float m0 = (jj0 < cnt2) ? 1.f : 0.f;
    float m1 = (jj1 < cnt2) ? 1.f : 0.f;
    float m2 = (jj2 < cnt2) ? 1.f : 0.f;
    float m3 = (jj3 < cnt2) ? 1.f : 0.f;
    floatx2 l0 = __builtin_amdgcn_cvt_pk_f32_fp8(u0, false);
    floatx2 h0 = __builtin_amdgcn_cvt_pk_f32_fp8(u0, true);
    floatx2 l1 = __builtin_amdgcn_cvt_pk_f32_fp8(u1, false);
    floatx2 h1 = __builtin_amdgcn_cvt_pk_f32_fp8(u1, true);
    floatx2 l2 = __builtin_amdgcn_cvt_pk_f32_fp8(u2, false);
    floatx2 h2 = __builtin_amdgcn_cvt_pk_f32_fp8(u2, true);
    floatx2 l3 = __builtin_amdgcn_cvt_pk_f32_fp8(u3, false);
    floatx2 h3 = __builtin_amdgcn_cvt_pk_f32_fp8(u3, true);
    a0 += m0 * l0.x; a1 += m0 * l0.y; a2 += m0 * h0.x; a3 += m0 * h0.y;
    a0 += m1 * l1.x; a1 += m1 * l1.y; a2 += m1 * h1.x; a3 += m1 * h1.y;
    a0 += m2 * l2.x; a1 += m2 * l2.y; a2 += m2 * h2.x; a3 += m2 * h2.y;
    a0 += m3 * l3.x; a1 += m3 * l3.y; a2 += m3 * h3.x; a3 += m3 * h3.y;
}

// ---------------- layer-2 aggregation + add hr ----------------------------
// 2 nodes per wave, masked a16m rounds jammed across nodes (8 u32 loads in
// flight, no serial tails). Two-stage shfl_xor reduce; lanes<16 / 16..31
// write each node's float4.
__global__ void k_agg2g(const int* __restrict__ row_start, const u16* __restrict__ csr16,
                        const u8* __restrict__ h28, const float* __restrict__ hrf,
                        const int* __restrict__ flags, void* __restrict__ out) {
    int t = threadIdx.x;
    int lane = t & 63;
    int n0 = blockIdx.x * 8 + (t >> 6) * 2;
    int n1 = n0 + 1;
    int g = lane >> 4;   // neighbor group 0..3
    int c = lane & 15;   // u32 column -> dims 4c..4c+3
    const unsigned int* h32 = (const unsigned int*)h28;

    int rsv = row_start[n0 + min(lane, 2)];
    int s0 = __shfl(rsv, 0), s1 = __shfl(rsv, 1), s2 = __shfl(rsv, 2);
    int ca = min(64, s1 - s0);
    int cb = min(64, s2 - s1);
    int mya = (lane < ca) ? (int)csr16[s0 + lane] : 0;
    int myb = (lane < cb) ? (int)csr16[s1 + lane] : 0;

    float a0 = 0.f, a1 = 0.f, a2 = 0.f, a3 = 0.f;
    float b0 = 0.f, b1 = 0.f, b2 = 0.f, b3 = 0.f;
    {
        int mx = max(ca, cb);
        for (int j = 0; j < mx; j += 16) {
            if (j < ca) a16m(h32, mya, j, ca, g, c, a0, a1, a2, a3);
            if (j < cb) a16m(h32, myb, j, cb, g, c, b0, b1, b2, b3);
        }
    }
    for (int base = s0 + 64; base < s1; base += 64) {   // rare deg>64 tail
        int cnt2 = min(64, s1 - base);
        int my = (lane < cnt2) ? (int)csr16[base + lane] : 0;
        for (int j = 0; j < cnt2; j += 16) a16m(h32, my, j, cnt2, g, c, a0, a1, a2, a3);
    }
    for (int base = s1 + 64; base < s2; base += 64) {
        int cnt2 = min(64, s2 - base);
        int my = (lane < cnt2) ? (int)csr16[base + lane] : 0;
        for (int j = 0; j < cnt2; j += 16) a16m(h32, my, j, cnt2, g, c, b0, b1, b2, b3);
    }
    a0 += __shfl_xor(a0, 32); a0 += __shfl_xor(a0, 16);
    a1 += __shfl_xor(a1, 32); a1 += __shfl_xor(a1, 16);
    a2 += __shfl_xor(a2, 32); a2 += __shfl_xor(a2, 16);
    a3 += __shfl_xor(a3, 32); a3 += __shfl_xor(a3, 16);
    b0 += __shfl_xor(b0, 32); b0 += __shfl_xor(b0, 16);
    b1 += __shfl_xor(b1, 32); b1 += __shfl_xor(b1, 16);
    b2 += __shfl_xor(b2, 32); b2 += __shfl_xor(b2, 16);
    b3 += __shfl_xor(b3, 32); b3 += __shfl_xor(b3, 16);
    if (lane < 16) {
        float inv = 1.0f / fmaxf((float)(s1 - s0), 1.0f);
        const float4 hr = *(const float4*)&hrf[(size_t)n0 * D_OUT + (c << 2)];
        float o0 = a0 * inv + hr.x;
        float o1 = a1 * inv + hr.y;
        float o2 = a2 * inv + hr.z;
        float o3 = a3 * inv + hr.w;
        if (flags[1]) {
            float4 v = {o0, o1, o2, o3};
            *(float4*)((float*)out + (size_t)n0 * D_OUT + (c << 2)) = v;
        } else {
            uint2 v;
            v.x = ((unsigned int)f2bfbits(o1) << 16) | f2bfbits(o0);
            v.y = ((unsigned int)f2bfbits(o3) << 16) | f2bfbits(o2);
            *(uint2*)((bf16*)out + (size_t)n0 * D_OUT + (c << 2)) = v;
        }
    } else if (lane < 32) {
        float inv = 1.0f / fmaxf((float)(s2 - s1), 1.0f);
        const float4 hr = *(const float4*)&hrf[(size_t)n1 * D_OUT + (c << 2)];
        float o0 = b0 * inv + hr.x;
        float o1 = b1 * inv + hr.y;
        float o2 = b2 * inv + hr.z;
        float o3 = b3 * inv + hr.w;
        if (flags[1]) {
            float4 v = {o0, o1, o2, o3};
            *(float4*)((float*)out + (size_t)n1 * D_OUT + (c << 2)) = v;
        } else {
            uint2 v;
            v.x = ((unsigned int)f2bfbits(o1) << 16) | f2bfbits(o0);
            v.y = ((unsigned int)f2bfbits(o3) << 16) | f2bfbits(o2);
            *(uint2*)((bf16*)out + (size_t)n1 * D_OUT + (c << 2)) = v;
        }
    }
}

extern "C" void kernel_launch(void* const* d_in, const int* in_sizes, int n_in,
                              void* d_out, int out_size, void* d_ws, size_t ws_size,
                              hipStream_t stream) {
    const void* x   = d_in[0];
    const int*  ei  = (const int*)d_in[1];
    const void* W1l = d_in[2];
    const void* b1  = d_in[3];
    const void* W1r = d_in[4];
    const void* W2l = d_in[5];
    const void* b2v = d_in[6];
    const void* W2r = d_in[7];

    const int N = NNODES;
    const int E = NEDGES;

    // ws layout (int units; large arrays 16B-aligned):
    int*          flags     = (int*)d_ws;
    u16*          src16     = (u16*)(flags + 4);            // E u16
    unsigned int* drpack    = (unsigned int*)(src16 + E);   // E u32
    int*          cnt       = (int*)(drpack + E);           // N
    int*          excl      = cnt + N;
    int*          bsum      = excl + N;
    int*          row_start = bsum + 256;                   // N+16
    u16*          csr16     = (u16*)(row_start + (N + 16)); // E u16
    bf16*         p1l       = (bf16*)(csr16 + E);           // 16384 bf16
    bf16*         p1r       = p1l + 16384;
    bf16*         p2l       = p1r + 16384;                  // 8192 bf16
    bf16*         p2r       = p2l + 8192;                   // 8192 bf16
    unsigned int* x8        = (unsigned int*)(p2r + 8192);  // N*128/4 u32
    u8*           h28       = (u8*)(x8 + (size_t)N * D_IN / 4);   // N*64 fp8
    float*        hrf       = (float*)(h28 + (size_t)N * D_OUT);  // N*64 f32

    k_setup<<<152 + 1024, 256, 0, stream>>>(cnt, N, (const unsigned int*)ei,
                                            (const unsigned int*)W1l, flags, x,
                                            W1l, W1r, W2l, W2r,
                                            p1l, p1r, p2l, p2r, x8);
    k_edges<<<(E + 255) / 256, 256, 0, stream>>>(ei, flags, src16, drpack, cnt);
    k_scan_a<<<NBLK, 256, 0, stream>>>(cnt, excl, bsum);
    k_scan_bc<<<NBLK, 256, 0, stream>>>(excl, bsum, row_start);
    k_scatter<<<(E + 255) / 256, 256, 0, stream>>>(src16, drpack, row_start, csr16);
    k_l1fused<<<N / 16, 512, 0, stream>>>(row_start, csr16, x, (const u16*)x8, flags,
                                          p1l, p1r, p2l, p2r, b1, b2v, h28, hrf);
    k_agg2g<<<N / 8, 256, 0, stream>>>(row_start, csr16, h28, hrf, flags, d_out);
}

// Round 5
// 196.234 us; speedup vs baseline: 1.1188x; 1.0021x over previous
//
#include <hip/hip_runtime.h>
#include <hip/hip_bf16.h>

typedef __hip_bfloat16 bf16;
typedef __attribute__((ext_vector_type(8))) short short8;
typedef __attribute__((ext_vector_type(4))) float floatx4;
typedef __attribute__((ext_vector_type(2))) float floatx2;
typedef unsigned short u16;
typedef unsigned char u8;

#define NNODES 50000
#define NEDGES 800000
#define D_IN  128
#define D_HID 128
#define D_OUT 64
#define NBLK  ((NNODES + 255) / 256)   // 196 scan blocks

__device__ __forceinline__ float bfbits2f(unsigned int u) {
    return __uint_as_float(u << 16);
}
__device__ __forceinline__ float b2f(bf16 v) { return __bfloat162float(v); }
__device__ __forceinline__ unsigned short f2bfbits(float f) {
    bf16 b = __float2bfloat16(f);
    return *(unsigned short*)&b;
}
__device__ __forceinline__ u8 f2fp8(float f) {
    return (u8)(__builtin_amdgcn_cvt_pk_fp8_f32(f, 0.f, 0, false) & 0xFF);
}
__device__ __forceinline__ float ld(const void* p, long long idx, int isf32) {
    if (isf32) return ((const float*)p)[idx];
    return b2f(((const bf16*)p)[idx]);
}

// ---- setup: zero cnt + detect (blocks 0..127), pack W (128..151),
//      build fp8 x-table (152..) -----------------------------------------
// flags[0] = 1 if edge_index is int64; flags[1] = 1 if float arrays are f32
__global__ void k_setup(int* __restrict__ cnt, int n,
                        const unsigned int* __restrict__ ei_words,
                        const unsigned int* __restrict__ w_words,
                        int* __restrict__ flags,
                        const void* __restrict__ x,
                        const void* __restrict__ W1l, const void* __restrict__ W1r,
                        const void* __restrict__ W2l, const void* __restrict__ W2r,
                        bf16* __restrict__ p1l, bf16* __restrict__ p1r,
                        bf16* __restrict__ p2l, bf16* __restrict__ p2r,
                        unsigned int* __restrict__ x8) {
    int b = blockIdx.x;
    if (b < 128) {
        if (b == 0) {
            __shared__ int cnt_zero, cnt_bf;
            if (threadIdx.x == 0) { cnt_zero = 0; cnt_bf = 0; }
            __syncthreads();
            int t = threadIdx.x;
            unsigned int we = ei_words[2 * t + 1];
            if (we == 0u) atomicAdd(&cnt_zero, 1);
            unsigned int ww = w_words[t];
            unsigned int lowexp = (ww >> 7) & 0xFFu;
            if (lowexp >= 0x60u && lowexp <= 0x7Bu) atomicAdd(&cnt_bf, 1);
            __syncthreads();
            if (threadIdx.x == 0) {
                flags[0] = (cnt_zero >= 240) ? 1 : 0;
                flags[1] = (cnt_bf >= 192) ? 0 : 1;
            }
        }
        int i = b * blockDim.x + threadIdx.x;
        int stride = 128 * blockDim.x;
        for (; i < n; i += stride) cnt[i] = 0;
        return;
    }
    // local dtype detection (flags not yet visible grid-wide)
    __shared__ int cnt_bf2;
    if (threadIdx.x == 0) cnt_bf2 = 0;
    __syncthreads();
    {
        unsigned int ww = w_words[threadIdx.x];
        unsigned int lowexp = (ww >> 7) & 0xFFu;
        if (lowexp >= 0x60u && lowexp <= 0x7Bu) atomicAdd(&cnt_bf2, 1);
    }
    __syncthreads();
    int isf32 = (cnt_bf2 >= 192) ? 0 : 1;
    if (b < 152) {  // ---- weight pack into MFMA B-fragment order
        int t = (b - 128) * 256 + threadIdx.x;
        if (t >= 6144) return;
        const void* Wm; bf16* dst; int NT; int base;
        if (t < 2048)      { Wm = W1l; dst = p1l; NT = 8; base = t; }
        else if (t < 4096) { Wm = W1r; dst = p1r; NT = 8; base = t - 2048; }
        else if (t < 5120) { Wm = W2l; dst = p2l; NT = 4; base = t - 4096; }
        else               { Wm = W2r; dst = p2r; NT = 4; base = t - 5120; }
        int lane = base & 63;
        int kt = (base >> 6) & 3;
        int nt = base >> 8;
        int Nmat = NT * 16;
        int krow = kt * 32 + ((lane >> 4) * 8);
        int col = nt * 16 + (lane & 15);
        #pragma unroll
        for (int j = 0; j < 8; j++) {
            float v = ld(Wm, (long long)(krow + j) * Nmat + col, isf32);
            dst[(((nt * 4 + kt) * 64 + lane) * 8) + j] = __float2bfloat16(v);
        }
        return;
    }
    // ---- fp8 (e4m3) x-table: 4 elems -> 1 u32 per thread, grid-stride
    const long long NU32 = (long long)NNODES * D_IN / 4;  // 1.6M
    long long i = (long long)(b - 152) * 256 + threadIdx.x;
    long long stride = (long long)(gridDim.x - 152) * 256;
    if (isf32) {
        const float4* xf = (const float4*)x;
        for (; i < NU32; i += stride) {
            float4 f = xf[i];
            unsigned int w0 = __builtin_amdgcn_cvt_pk_fp8_f32(f.x, f.y, 0, false);
            w0 = __builtin_amdgcn_cvt_pk_fp8_f32(f.z, f.w, w0, true);
            x8[i] = w0;
        }
    } else {
        const ushort4* xb = (const ushort4*)x;
        for (; i < NU32; i += stride) {
            ushort4 s = xb[i];
            float f0 = bfbits2f(s.x), f1 = bfbits2f(s.y);
            float f2 = bfbits2f(s.z), f3 = bfbits2f(s.w);
            unsigned int w0 = __builtin_amdgcn_cvt_pk_fp8_f32(f0, f1, 0, false);
            w0 = __builtin_amdgcn_cvt_pk_fp8_f32(f2, f3, w0, true);
            x8[i] = w0;
        }
    }
}

// ------- edges: canonicalize + histogram + per-edge rank (packed w/ dst) ----
// drpack[e] = (rank << 16) | dst   (both < 65536)
__global__ void k_edges(const int* __restrict__ ei, const int* __restrict__ flags,
                        u16* __restrict__ src16, unsigned int* __restrict__ drpack,
                        int* __restrict__ cnt) {
    int e = blockIdx.x * blockDim.x + threadIdx.x;
    if (e >= NEDGES) return;
    int s, d;
    if (flags[0]) { s = ei[2 * e]; d = ei[2 * (NEDGES + e)]; }
    else          { s = ei[e];     d = ei[NEDGES + e]; }
    src16[e] = (u16)s;
    int rank = atomicAdd(&cnt[d], 1);
    drpack[e] = ((unsigned int)rank << 16) | (unsigned int)d;
}

// ---------------- 2-phase exclusive scan ----------------
__global__ void k_scan_a(const int* __restrict__ cnt, int* __restrict__ excl,
                         int* __restrict__ bsum) {
    __shared__ int s[256];
    int t = threadIdx.x;
    int i = blockIdx.x * 256 + t;
    int v = (i < NNODES) ? cnt[i] : 0;
    s[t] = v;
    __syncthreads();
    for (int off = 1; off < 256; off <<= 1) {
        int u = (t >= off) ? s[t - off] : 0;
        __syncthreads();
        s[t] += u;
        __syncthreads();
    }
    if (i < NNODES) excl[i] = s[t] - v;
    if (t == 255) bsum[blockIdx.x] = s[255];
}

// every block scans bsum in LDS (redundant but cheap), picks its offset,
// then writes row_start — merges old scan_b+scan_c into one launch
__global__ void k_scan_bc(const int* __restrict__ excl, const int* __restrict__ bsum,
                          int* __restrict__ row_start) {
    __shared__ int s[256];
    __shared__ int bo;
    int t = threadIdx.x;
    int v = (t < NBLK) ? bsum[t] : 0;
    s[t] = v;
    __syncthreads();
    for (int off = 1; off < 256; off <<= 1) {
        int u = (t >= off) ? s[t - off] : 0;
        __syncthreads();
        s[t] += u;
        __syncthreads();
    }
    if (t == 0) bo = s[blockIdx.x] - bsum[blockIdx.x];   // exclusive offset
    __syncthreads();
    int i = blockIdx.x * 256 + t;
    if (i < NNODES) row_start[i] = bo + excl[i];
    if (i == 0) row_start[NNODES] = NEDGES;
}

// ---------------- scatter edges into u16 CSR (no atomics) ----------------
__global__ void k_scatter(const u16* __restrict__ src16,
                          const unsigned int* __restrict__ drpack,
                          const int* __restrict__ row_start,
                          u16* __restrict__ csr16) {
    int e = blockIdx.x * blockDim.x + threadIdx.x;
    if (e >= NEDGES) return;
    unsigned int dp = drpack[e];
    int d = (int)(dp & 0xFFFFu);
    int r = (int)(dp >> 16);
    csr16[row_start[d] + r] = src16[e];
}

// ---- masked 16-neighbor round (u32, half-wave split) ---------------------
// Lane h=l>>5 takes neighbor group (j+h*8 .. j+h*8+7), c=l&31 covers dims
// 4c..4c+3 (one u32 = 4 fp8). 8 loads cover 16 neighbors; masks fold the
// tail so deg<=16 nodes finish in ONE round (one vmcnt wait). OOB lanes
// hold index 0 -> loads safe, contribution zeroed.
__device__ __forceinline__ void g16m(const unsigned int* __restrict__ x8w, int my,
                                     int j, int cnt2, int h, int c,
                                     float& a0, float& a1, float& a2, float& a3) {
    int jb = j + h * 8;
    int i0 = __shfl(my, jb + 0), i1 = __shfl(my, jb + 1);
    int i2 = __shfl(my, jb + 2), i3 = __shfl(my, jb + 3);
    int i4 = __shfl(my, jb + 4), i5 = __shfl(my, jb + 5);
    int i6 = __shfl(my, jb + 6), i7 = __shfl(my, jb + 7);
    unsigned int u0 = x8w[((unsigned)i0 << 5) + c];
    unsigned int u1 = x8w[((unsigned)i1 << 5) + c];
    unsigned int u2 = x8w[((unsigned)i2 << 5) + c];
    unsigned int u3 = x8w[((unsigned)i3 << 5) + c];
    unsigned int u4 = x8w[((unsigned)i4 << 5) + c];
    unsigned int u5 = x8w[((unsigned)i5 << 5) + c];
    unsigned int u6 = x8w[((unsigned)i6 << 5) + c];
    unsigned int u7 = x8w[((unsigned)i7 << 5) + c];
    float m0 = (jb + 0 < cnt2) ? 1.f : 0.f;
    float m1 = (jb + 1 < cnt2) ? 1.f : 0.f;
    float m2 = (jb + 2 < cnt2) ? 1.f : 0.f;
    float m3 = (jb + 3 < cnt2) ? 1.f : 0.f;
    float m4 = (jb + 4 < cnt2) ? 1.f : 0.f;
    float m5 = (jb + 5 < cnt2) ? 1.f : 0.f;
    float m6 = (jb + 6 < cnt2) ? 1.f : 0.f;
    float m7 = (jb + 7 < cnt2) ? 1.f : 0.f;
    floatx2 l0 = __builtin_amdgcn_cvt_pk_f32_fp8(u0, false);
    floatx2 h0 = __builtin_amdgcn_cvt_pk_f32_fp8(u0, true);
    floatx2 l1 = __builtin_amdgcn_cvt_pk_f32_fp8(u1, false);
    floatx2 h1 = __builtin_amdgcn_cvt_pk_f32_fp8(u1, true);
    floatx2 l2 = __builtin_amdgcn_cvt_pk_f32_fp8(u2, false);
    floatx2 h2 = __builtin_amdgcn_cvt_pk_f32_fp8(u2, true);
    floatx2 l3 = __builtin_amdgcn_cvt_pk_f32_fp8(u3, false);
    floatx2 h3 = __builtin_amdgcn_cvt_pk_f32_fp8(u3, true);
    floatx2 l4 = __builtin_amdgcn_cvt_pk_f32_fp8(u4, false);
    floatx2 h4 = __builtin_amdgcn_cvt_pk_f32_fp8(u4, true);
    floatx2 l5 = __builtin_amdgcn_cvt_pk_f32_fp8(u5, false);
    floatx2 h5 = __builtin_amdgcn_cvt_pk_f32_fp8(u5, true);
    floatx2 l6 = __builtin_amdgcn_cvt_pk_f32_fp8(u6, false);
    floatx2 h6 = __builtin_amdgcn_cvt_pk_f32_fp8(u6, true);
    floatx2 l7 = __builtin_amdgcn_cvt_pk_f32_fp8(u7, false);
    floatx2 h7 = __builtin_amdgcn_cvt_pk_f32_fp8(u7, true);
    a0 += m0 * l0.x; a1 += m0 * l0.y; a2 += m0 * h0.x; a3 += m0 * h0.y;
    a0 += m1 * l1.x; a1 += m1 * l1.y; a2 += m1 * h1.x; a3 += m1 * h1.y;
    a0 += m2 * l2.x; a1 += m2 * l2.y; a2 += m2 * h2.x; a3 += m2 * h2.y;
    a0 += m3 * l3.x; a1 += m3 * l3.y; a2 += m3 * h3.x; a3 += m3 * h3.y;
    a0 += m4 * l4.x; a1 += m4 * l4.y; a2 += m4 * h4.x; a3 += m4 * h4.y;
    a0 += m5 * l5.x; a1 += m5 * l5.y; a2 += m5 * h5.x; a3 += m5 * h5.y;
    a0 += m6 * l6.x; a1 += m6 * l6.y; a2 += m6 * h6.x; a3 += m6 * h6.y;
    a0 += m7 * l7.x; a1 += m7 * l7.y; a2 += m7 * h7.x; a3 += m7 * h7.y;
}

// -------- fused: fp8 CSR mean-gather (LDS) + MFMA layer1 + pre-transforms --
// 16 nodes/block, 8 waves (512 thr): wave w gathers nodes w*2, w*2+1.
// Gather = u32 half-wave g16m rounds, UNCONDITIONAL dual-node jam (no
// branches between the two load clusters -> 16 loads co-issued; deg<=16
// pair completes in one round / one wait).
// Phase 2 (MFMA):
//   H  = relu(mean @ W1_l + b1 + x @ W1_r)   [16 x 128] — wave w owns col-tile w
//   H2 = H @ W2_l                             [16 x 64]  -> h28 (fp8, waves 0-3)
//   HR = H @ W2_r + b2                        [16 x 64]  -> hrf (f32, waves 0-3)
__global__ __launch_bounds__(512) void k_l1fused(
        const int* __restrict__ row_start, const u16* __restrict__ csr16,
        const void* __restrict__ x, const unsigned int* __restrict__ x8w,
        const int* __restrict__ flags,
        const bf16* __restrict__ p1l, const bf16* __restrict__ p1r,
        const bf16* __restrict__ p2l, const bf16* __restrict__ p2r,
        const void* __restrict__ b1, const void* __restrict__ b2v,
        u8* __restrict__ h28, float* __restrict__ hrf) {
    __shared__ bf16 ms[16][136];   // +8 pad -> 2-way-free LDS banking
    __shared__ bf16 xs[16][136];   // staged x rows (bf16)
    __shared__ bf16 hs[16][136];
    __shared__ u8 h2s8[16][72];    // 72 = 8*9: rows stay 8B-aligned
    __shared__ float hrs[16][68];
    int t = threadIdx.x;
    int w = t >> 6;    // 0..7
    int l = t & 63;
    int nb = blockIdx.x * 16;
    int isf32 = flags[1];
    int r0 = w * 2, r1 = r0 + 1;
    int h = l >> 5;    // neighbor-group half
    int c = l & 31;    // u32 column -> dims 4c..4c+3

    // 3 row_start values per wave, one coop load + shfl
    int rsv = row_start[nb + r0 + min(l, 2)];
    int s0 = __shfl(rsv, 0), s1 = __shfl(rsv, 1), s2 = __shfl(rsv, 2);

    // prefetch both nodes' first index chunks (pays idx latency once)
    int ca = min(64, s1 - s0);
    int cb = min(64, s2 - s1);
    int mya = (l < ca) ? (int)csr16[s0 + l] : 0;
    int myb = (l < cb) ? (int)csr16[s1 + l] : 0;

    // stage this wave's two x rows into LDS as bf16 (dims 2l, 2l+1)
    {
        long long ro0 = (long long)(nb + r0) * D_IN + 2 * l;
        long long ro1 = (long long)(nb + r1) * D_IN + 2 * l;
        unsigned int px0, px1;
        if (isf32) {
            float2 v0 = *(const float2*)((const float*)x + ro0);
            float2 v1 = *(const float2*)((const float*)x + ro1);
            px0 = ((unsigned int)f2bfbits(v0.y) << 16) | f2bfbits(v0.x);
            px1 = ((unsigned int)f2bfbits(v1.y) << 16) | f2bfbits(v1.x);
        } else {
            px0 = *(const unsigned int*)((const bf16*)x + ro0);
            px1 = *(const unsigned int*)((const bf16*)x + ro1);
        }
        *(unsigned int*)((bf16*)&xs[r0][0] + 2 * l) = px0;
        *(unsigned int*)((bf16*)&xs[r1][0] + 2 * l) = px1;
    }

    // ---- phase 1: fp8 gather — masked u32 rounds, unconditional jam
    float aa0 = 0.f, aa1 = 0.f, aa2 = 0.f, aa3 = 0.f;
    float bb0 = 0.f, bb1 = 0.f, bb2 = 0.f, bb3 = 0.f;
    {
        int mx = max(ca, cb);
        for (int j = 0; j < mx; j += 16) {
            g16m(x8w, mya, j, ca, h, c, aa0, aa1, aa2, aa3);
            g16m(x8w, myb, j, cb, h, c, bb0, bb1, bb2, bb3);
        }
    }
    for (int base = s0 + 64; base < s1; base += 64) {   // rare deg>64 tail
        int cnt2 = min(64, s1 - base);
        int my = (l < cnt2) ? (int)csr16[base + l] : 0;
        for (int j = 0; j < cnt2; j += 16) g16m(x8w, my, j, cnt2, h, c, aa0, aa1, aa2, aa3);
    }
    for (int base = s1 + 64; base < s2; base += 64) {
        int cnt2 = min(64, s2 - base);
        int my = (l < cnt2) ? (int)csr16[base + l] : 0;
        for (int j = 0; j < cnt2; j += 16) g16m(x8w, my, j, cnt2, h, c, bb0, bb1, bb2, bb3);
    }
    // combine halves; lanes<32 write node r0, lanes>=32 write node r1
    aa0 += __shfl_xor(aa0, 32); aa1 += __shfl_xor(aa1, 32);
    aa2 += __shfl_xor(aa2, 32); aa3 += __shfl_xor(aa3, 32);
    bb0 += __shfl_xor(bb0, 32); bb1 += __shfl_xor(bb1, 32);
    bb2 += __shfl_xor(bb2, 32); bb3 += __shfl_xor(bb3, 32);
    if (l < 32) {
        float inv = 1.0f / fmaxf((float)(s1 - s0), 1.0f);
        uint2 pk;
        pk.x = ((unsigned int)f2bfbits(aa1 * inv) << 16) | f2bfbits(aa0 * inv);
        pk.y = ((unsigned int)f2bfbits(aa3 * inv) << 16) | f2bfbits(aa2 * inv);
        *(uint2*)((bf16*)&ms[r0][0] + (c << 2)) = pk;
    } else {
        float inv = 1.0f / fmaxf((float)(s2 - s1), 1.0f);
        uint2 pk;
        pk.x = ((unsigned int)f2bfbits(bb1 * inv) << 16) | f2bfbits(bb0 * inv);
        pk.y = ((unsigned int)f2bfbits(bb3 * inv) << 16) | f2bfbits(bb2 * inv);
        *(uint2*)((bf16*)&ms[r1][0] + (c << 2)) = pk;
    }
    __syncthreads();

    // ---- phase 2: MFMA — wave w owns layer-1 column tile nt = w
    int m = l & 15;
    int quad = l >> 4;
    floatx4 acc0 = {0.f, 0.f, 0.f, 0.f};
    #pragma unroll
    for (int kt = 0; kt < 4; kt++) {
        short8 amv = *(const short8*)&ms[m][kt * 32 + quad * 8];
        short8 axv = *(const short8*)&xs[m][kt * 32 + quad * 8];
        short8 bl0 = *(const short8*)(p1l + (((w * 4 + kt) * 64 + l) * 8));
        short8 br0 = *(const short8*)(p1r + (((w * 4 + kt) * 64 + l) * 8));
        acc0 = __builtin_amdgcn_mfma_f32_16x16x32_bf16(amv, bl0, acc0, 0, 0, 0);
        acc0 = __builtin_amdgcn_mfma_f32_16x16x32_bf16(axv, br0, acc0, 0, 0, 0);
    }
    int c0 = w * 16 + m;
    float bias0 = ld(b1, c0, isf32);
    #pragma unroll
    for (int r = 0; r < 4; r++) {
        hs[quad * 4 + r][c0] = __float2bfloat16(fmaxf(acc0[r] + bias0, 0.f));
    }
    __syncthreads();
    if (w < 4) {       // layer 2: 4 waves cover the 64 output cols
        floatx4 acc2 = {0.f, 0.f, 0.f, 0.f};
        floatx4 acc3 = {0.f, 0.f, 0.f, 0.f};
        #pragma unroll
        for (int kt = 0; kt < 4; kt++) {
            short8 ah = *(const short8*)&hs[m][kt * 32 + quad * 8];
            short8 bw = *(const short8*)(p2l + (((w * 4 + kt) * 64 + l) * 8));
            short8 bz = *(const short8*)(p2r + (((w * 4 + kt) * 64 + l) * 8));
            acc2 = __builtin_amdgcn_mfma_f32_16x16x32_bf16(ah, bw, acc2, 0, 0, 0);
            acc3 = __builtin_amdgcn_mfma_f32_16x16x32_bf16(ah, bz, acc3, 0, 0, 0);
        }
        int c2 = w * 16 + m;
        float bias2 = ld(b2v, c2, isf32);
        #pragma unroll
        for (int r = 0; r < 4; r++) {
            h2s8[quad * 4 + r][c2] = f2fp8(acc2[r]);      // f32 -> fp8 direct
            hrs[quad * 4 + r][c2] = acc3[r] + bias2;
        }
    }
    __syncthreads();
    if (t < 128) {
        int node = t >> 3, col0 = (t & 7) * 8;
        uint2 v = *(const uint2*)&h2s8[node][col0];
        *(uint2*)(h28 + (long long)(nb + node) * D_OUT + col0) = v;
    }
    if (t < 256) {
        int node = t >> 4, col0 = (t & 15) * 4;
        float4 v = *(const float4*)&hrs[node][col0];
        *(float4*)(hrf + (long long)(nb + node) * D_OUT + col0) = v;
    }
}

// ---- masked 16-wide agg2 round: quarter-wave per row, dims 4c..4c+3 ------
// 4 loads cover neighbors j..j+15; per-load mask zeroes OOB contributions.
__device__ __forceinline__ void a16m(const unsigned int* __restrict__ h32, int my,
                                     int j, int cnt2, int g, int c,
                                     float& a0, float& a1, float& a2, float& a3) {
    int jj0 = j + g, jj1 = j + 4 + g, jj2 = j + 8 + g, jj3 = j + 12 + g;
    int i0 = __shfl(my, jj0);
    int i1 = __shfl(my, jj1);
    int i2 = __shfl(my, jj2);
    int i3 = __shfl(my, jj3);
    unsigned int u0 = h32[(size_t)i0 * 16 + c];
    unsigned int u1 = h32[(size_t)i1 * 16 + c];
    unsigned int u2 = h32[(size_t)i2 * 16 + c];
    unsigned int u3 = h32[(size_t)i3 * 16 + c];
    float m0 = (jj0 < cnt2) ? 1.f : 0.f;
    float m1 = (jj1 < cnt2) ? 1.f : 0.f;
    float m2 = (jj2 < cnt2) ? 1.f : 0.f;
    float m3 = (jj3 < cnt2) ? 1.f : 0.f;
    floatx2 l0 = __builtin_amdgcn_cvt_pk_f32_fp8(u0, false);
    floatx2 h0 = __builtin_amdgcn_cvt_pk_f32_fp8(u0, true);
    floatx2 l1 = __builtin_amdgcn_cvt_pk_f32_fp8(u1, false);
    floatx2 h1 = __builtin_amdgcn_cvt_pk_f32_fp8(u1, true);
    floatx2 l2 = __builtin_amdgcn_cvt_pk_f32_fp8(u2, false);
    floatx2 h2 = __builtin_amdgcn_cvt_pk_f32_fp8(u2, true);
    floatx2 l3 = __builtin_amdgcn_cvt_pk_f32_fp8(u3, false);
    floatx2 h3 = __builtin_amdgcn_cvt_pk_f32_fp8(u3, true);
    a0 += m0 * l0.x; a1 += m0 * l0.y; a2 += m0 * h0.x; a3 += m0 * h0.y;
    a0 += m1 * l1.x; a1 += m1 * l1.y; a2 += m1 * h1.x; a3 += m1 * h1.y;
    a0 += m2 * l2.x; a1 += m2 * l2.y; a2 += m2 * h2.x; a3 += m2 * h2.y;
    a0 += m3 * l3.x; a1 += m3 * l3.y; a2 += m3 * h3.x; a3 += m3 * h3.y;
}

// ---------------- layer-2 aggregation + add hr ----------------------------
// 2 nodes per wave, masked a16m rounds with UNCONDITIONAL dual-node jam
// (8 u32 loads co-issued, no serial tails, no jam-breaking branches).
// hrf float4 prefetched before the gather so its latency hides under it.
__global__ void k_agg2g(const int* __restrict__ row_start, const u16* __restrict__ csr16,
                        const u8* __restrict__ h28, const float* __restrict__ hrf,
                        const int* __restrict__ flags, void* __restrict__ out) {
    int t = threadIdx.x;
    int lane = t & 63;
    int n0 = blockIdx.x * 8 + (t >> 6) * 2;
    int n1 = n0 + 1;
    int g = lane >> 4;   // neighbor group 0..3
    int c = lane & 15;   // u32 column -> dims 4c..4c+3
    const unsigned int* h32 = (const unsigned int*)h28;

    int rsv = row_start[n0 + min(lane, 2)];
    int s0 = __shfl(rsv, 0), s1 = __shfl(rsv, 1), s2 = __shfl(rsv, 2);
    int ca = min(64, s1 - s0);
    int cb = min(64, s2 - s1);
    int mya = (lane < ca) ? (int)csr16[s0 + lane] : 0;
    int myb = (lane < cb) ? (int)csr16[s1 + lane] : 0;

    // prefetch this lane's hr float4 (lanes<16: n0, lanes 16..31: n1)
    float4 hr = {0.f, 0.f, 0.f, 0.f};
    if (lane < 32) {
        int nn = (lane < 16) ? n0 : n1;
        hr = *(const float4*)&hrf[(size_t)nn * D_OUT + (c << 2)];
    }

    float a0 = 0.f, a1 = 0.f, a2 = 0.f, a3 = 0.f;
    float b0 = 0.f, b1 = 0.f, b2 = 0.f, b3 = 0.f;
    {
        int mx = max(ca, cb);
        for (int j = 0; j < mx; j += 16) {
            a16m(h32, mya, j, ca, g, c, a0, a1, a2, a3);
            a16m(h32, myb, j, cb, g, c, b0, b1, b2, b3);
        }
    }
    for (int base = s0 + 64; base < s1; base += 64) {   // rare deg>64 tail
        int cnt2 = min(64, s1 - base);
        int my = (lane < cnt2) ? (int)csr16[base + lane] : 0;
        for (int j = 0; j < cnt2; j += 16) a16m(h32, my, j, cnt2, g, c, a0, a1, a2, a3);
    }
    for (int base = s1 + 64; base < s2; base += 64) {
        int cnt2 = min(64, s2 - base);
        int my = (lane < cnt2) ? (int)csr16[base + lane] : 0;
        for (int j = 0; j < cnt2; j += 16) a16m(h32, my, j, cnt2, g, c, b0, b1, b2, b3);
    }
    a0 += __shfl_xor(a0, 32); a0 += __shfl_xor(a0, 16);
    a1 += __shfl_xor(a1, 32); a1 += __shfl_xor(a1, 16);
    a2 += __shfl_xor(a2, 32); a2 += __shfl_xor(a2, 16);
    a3 += __shfl_xor(a3, 32); a3 += __shfl_xor(a3, 16);
    b0 += __shfl_xor(b0, 32); b0 += __shfl_xor(b0, 16);
    b1 += __shfl_xor(b1, 32); b1 += __shfl_xor(b1, 16);
    b2 += __shfl_xor(b2, 32); b2 += __shfl_xor(b2, 16);
    b3 += __shfl_xor(b3, 32); b3 += __shfl_xor(b3, 16);
    if (lane < 16) {
        float inv = 1.0f / fmaxf((float)(s1 - s0), 1.0f);
        float o0 = a0 * inv + hr.x;
        float o1 = a1 * inv + hr.y;
        float o2 = a2 * inv + hr.z;
        float o3 = a3 * inv + hr.w;
        if (flags[1]) {
            float4 v = {o0, o1, o2, o3};
            *(float4*)((float*)out + (size_t)n0 * D_OUT + (c << 2)) = v;
        } else {
            uint2 v;
            v.x = ((unsigned int)f2bfbits(o1) << 16) | f2bfbits(o0);
            v.y = ((unsigned int)f2bfbits(o3) << 16) | f2bfbits(o2);
            *(uint2*)((bf16*)out + (size_t)n0 * D_OUT + (c << 2)) = v;
        }
    } else if (lane < 32) {
        float inv = 1.0f / fmaxf((float)(s2 - s1), 1.0f);
        float o0 = b0 * inv + hr.x;
        float o1 = b1 * inv + hr.y;
        float o2 = b2 * inv + hr.z;
        float o3 = b3 * inv + hr.w;
        if (flags[1]) {
            float4 v = {o0, o1, o2, o3};
            *(float4*)((float*)out + (size_t)n1 * D_OUT + (c << 2)) = v;
        } else {
            uint2 v;
            v.x = ((unsigned int)f2bfbits(o1) << 16) | f2bfbits(o0);
            v.y = ((unsigned int)f2bfbits(o3) << 16) | f2bfbits(o2);
            *(uint2*)((bf16*)out + (size_t)n1 * D_OUT + (c << 2)) = v;
        }
    }
}

extern "C" void kernel_launch(void* const* d_in, const int* in_sizes, int n_in,
                              void* d_out, int out_size, void* d_ws, size_t ws_size,
                              hipStream_t stream) {
    const void* x   = d_in[0];
    const int*  ei  = (const int*)d_in[1];
    const void* W1l = d_in[2];
    const void* b1  = d_in[3];
    const void* W1r = d_in[4];
    const void* W2l = d_in[5];
    const void* b2v = d_in[6];
    const void* W2r = d_in[7];

    const int N = NNODES;
    const int E = NEDGES;

    // ws layout (int units; large arrays 16B-aligned):
    int*          flags     = (int*)d_ws;
    u16*          src16     = (u16*)(flags + 4);            // E u16
    unsigned int* drpack    = (unsigned int*)(src16 + E);   // E u32
    int*          cnt       = (int*)(drpack + E);           // N
    int*          excl      = cnt + N;
    int*          bsum      = excl + N;
    int*          row_start = bsum + 256;                   // N+16
    u16*          csr16     = (u16*)(row_start + (N + 16)); // E u16
    bf16*         p1l       = (bf16*)(csr16 + E);           // 16384 bf16
    bf16*         p1r       = p1l + 16384;
    bf16*         p2l       = p1r + 16384;                  // 8192 bf16
    bf16*         p2r       = p2l + 8192;                   // 8192 bf16
    unsigned int* x8        = (unsigned int*)(p2r + 8192);  // N*128/4 u32
    u8*           h28       = (u8*)(x8 + (size_t)N * D_IN / 4);   // N*64 fp8
    float*        hrf       = (float*)(h28 + (size_t)N * D_OUT);  // N*64 f32

    k_setup<<<152 + 1024, 256, 0, stream>>>(cnt, N, (const unsigned int*)ei,
                                            (const unsigned int*)W1l, flags, x,
                                            W1l, W1r, W2l, W2r,
                                            p1l, p1r, p2l, p2r, x8);
    k_edges<<<(E + 255) / 256, 256, 0, stream>>>(ei, flags, src16, drpack, cnt);
    k_scan_a<<<NBLK, 256, 0, stream>>>(cnt, excl, bsum);
    k_scan_bc<<<NBLK, 256, 0, stream>>>(excl, bsum, row_start);
    k_scatter<<<(E + 255) / 256, 256, 0, stream>>>(src16, drpack, row_start, csr16);
    k_l1fused<<<N / 16, 512, 0, stream>>>(row_start, csr16, x, x8, flags,
                                          p1l, p1r, p2l, p2r, b1, b2v, h28, hrf);
    k_agg2g<<<N / 8, 256, 0, stream>>>(row_start, csr16, h28, hrf, flags, d_out);
}